// Round 1
// baseline (1271.066 us; speedup 1.0000x reference)
//
#include <hip/hip_runtime.h>
#include <math.h>

#define NN 65536   // nodes
#define NE 524288  // edges
#define NG 2048    // graphs
#define HD 256     // hidden
#define NL 50      // noise levels

typedef unsigned short u16;
typedef __attribute__((ext_vector_type(8))) short short8;
typedef __attribute__((ext_vector_type(4))) float f32x4;

__device__ __forceinline__ float bf2f(u16 h){
  union{unsigned int u; float f;} v; v.u = ((unsigned int)h)<<16; return v.f;
}
__device__ __forceinline__ u16 f2bf(float f){
  union{float f; unsigned int u;} v; v.f=f;
  return (u16)((v.u + 0x7FFFu + ((v.u>>16)&1u))>>16);
}
__device__ __forceinline__ float silu_f(float v){ return v/(1.0f+__expf(-v)); }

// ---------------- Kabsch path ----------------

__global__ void k_sigma(const float* __restrict__ pos, const float* __restrict__ noise,
                        const int* __restrict__ n2g, const int* __restrict__ nl,
                        float* __restrict__ sigma, float* __restrict__ ppin,
                        float* __restrict__ sum_pos, float* __restrict__ sum_pp,
                        float* __restrict__ cnt){
  int i = blockIdx.x*256 + threadIdx.x;
  if(i>=NN) return;
  int g = n2g[i];
  int l = nl[g];
  const double L0 =  2.3025850929940456840;  // ln 10
  const double L1 = -4.6051701859880913680;  // ln 0.01
  float sg = (float)exp(L0 + (double)l*(L1-L0)/49.0);
  sigma[i]=sg;
  float px=pos[i*3+0], py=pos[i*3+1], pz=pos[i*3+2];
  float qx=px+noise[i*3+0]*sg, qy=py+noise[i*3+1]*sg, qz=pz+noise[i*3+2]*sg;
  ppin[i*3+0]=qx; ppin[i*3+1]=qy; ppin[i*3+2]=qz;
  atomicAdd(&sum_pos[g*3+0],px); atomicAdd(&sum_pos[g*3+1],py); atomicAdd(&sum_pos[g*3+2],pz);
  atomicAdd(&sum_pp [g*3+0],qx); atomicAdd(&sum_pp [g*3+1],qy); atomicAdd(&sum_pp [g*3+2],qz);
  atomicAdd(&cnt[g],1.0f);
}

__global__ void k_center(const float* __restrict__ sum_pos, const float* __restrict__ sum_pp,
                         const float* __restrict__ cnt,
                         float* __restrict__ center, float* __restrict__ pcenter){
  int g = blockIdx.x*256+threadIdx.x; if(g>=NG) return;
  float c = fmaxf(cnt[g],1.0f);
  #pragma unroll
  for(int d=0;d<3;d++){ center[g*3+d]=sum_pos[g*3+d]/c; pcenter[g*3+d]=sum_pp[g*3+d]/c; }
}

__global__ void k_H(const float* __restrict__ pos, const float* __restrict__ ppin,
                    const int* __restrict__ n2g, const float* __restrict__ center,
                    const float* __restrict__ pcenter, float* __restrict__ Hm){
  int i = blockIdx.x*256+threadIdx.x; if(i>=NN) return;
  int g=n2g[i];
  float a0=ppin[i*3+0]-pcenter[g*3+0];
  float a1=ppin[i*3+1]-pcenter[g*3+1];
  float a2=ppin[i*3+2]-pcenter[g*3+2];
  float b0=pos[i*3+0]-center[g*3+0];
  float b1=pos[i*3+1]-center[g*3+1];
  float b2=pos[i*3+2]-center[g*3+2];
  // H[g][r][c] += a_r * b_c
  atomicAdd(&Hm[g*9+0],a0*b0); atomicAdd(&Hm[g*9+1],a0*b1); atomicAdd(&Hm[g*9+2],a0*b2);
  atomicAdd(&Hm[g*9+3],a1*b0); atomicAdd(&Hm[g*9+4],a1*b1); atomicAdd(&Hm[g*9+5],a1*b2);
  atomicAdd(&Hm[g*9+6],a2*b0); atomicAdd(&Hm[g*9+7],a2*b1); atomicAdd(&Hm[g*9+8],a2*b2);
}

// R = polar orthogonal factor of H^T  ( == V U^T with H = U S V^T ), Newton iteration.
__global__ void k_polar(const float* __restrict__ Hm, const float* __restrict__ center,
                        const float* __restrict__ pcenter,
                        float* __restrict__ R, float* __restrict__ T){
  int g = blockIdx.x*256+threadIdx.x; if(g>=NG) return;
  float X[3][3];
  #pragma unroll
  for(int r=0;r<3;r++)
    #pragma unroll
    for(int c=0;c<3;c++) X[r][c]=Hm[g*9 + c*3 + r];   // X = H^T
  float nf=0.f;
  #pragma unroll
  for(int r=0;r<3;r++) for(int c=0;c<3;c++) nf += X[r][c]*X[r][c];
  nf = sqrtf(nf);
  if(nf < 1e-20f){
    #pragma unroll
    for(int r=0;r<3;r++) for(int c=0;c<3;c++) X[r][c]=(r==c)?1.f:0.f;
  } else {
    float s0=1.f/nf;
    #pragma unroll
    for(int r=0;r<3;r++) for(int c=0;c<3;c++) X[r][c]*=s0;
    for(int it=0; it<30; ++it){
      float a=X[0][0],b=X[0][1],c=X[0][2];
      float d=X[1][0],e=X[1][1],f=X[1][2];
      float gg=X[2][0],h=X[2][1],ii=X[2][2];
      float A_= e*ii-f*h, B_=-(d*ii-f*gg), C_= d*h-e*gg;
      float D_=-(b*ii-c*h), E_= a*ii-c*gg, F_=-(a*h-b*gg);
      float G_= b*f-c*e,  H_=-(a*f-c*d),  I_= a*e-b*d;
      float det = a*A_ + b*B_ + c*C_;
      if(!(fabsf(det) > 1e-25f)){
        if(it==0){ // degenerate -> identity
          for(int r=0;r<3;r++) for(int cc=0;cc<3;cc++) X[r][cc]=(r==cc)?1.f:0.f;
        }
        break;
      }
      float si = 0.5f/det;
      // inv(X)^T = cof/det with cof rows (A_,B_,C_),(D_,E_,F_),(G_,H_,I_)
      float Y00=0.5f*a + si*A_, Y01=0.5f*b + si*B_, Y02=0.5f*c + si*C_;
      float Y10=0.5f*d + si*D_, Y11=0.5f*e + si*E_, Y12=0.5f*f + si*F_;
      float Y20=0.5f*gg+ si*G_, Y21=0.5f*h + si*H_, Y22=0.5f*ii+ si*I_;
      X[0][0]=Y00; X[0][1]=Y01; X[0][2]=Y02;
      X[1][0]=Y10; X[1][1]=Y11; X[1][2]=Y12;
      X[2][0]=Y20; X[2][1]=Y21; X[2][2]=Y22;
    }
  }
  float pcx=pcenter[g*3+0], pcy=pcenter[g*3+1], pcz=pcenter[g*3+2];
  #pragma unroll
  for(int r=0;r<3;r++){
    T[g*3+r] = center[g*3+r] - (X[r][0]*pcx + X[r][1]*pcy + X[r][2]*pcz);
    #pragma unroll
    for(int c=0;c<3;c++) R[g*9+r*3+c]=X[r][c];
  }
}

__global__ void k_posp(const float* __restrict__ ppin, const float* __restrict__ pos,
                       const float* __restrict__ sigma, const int* __restrict__ n2g,
                       const float* __restrict__ R, const float* __restrict__ T,
                       float* __restrict__ posp, float* __restrict__ target){
  int i = blockIdx.x*256+threadIdx.x; if(i>=NN) return;
  int g=n2g[i];
  float qx=ppin[i*3+0], qy=ppin[i*3+1], qz=ppin[i*3+2];
  float px,py,pz;
  px = R[g*9+0]*qx + R[g*9+1]*qy + R[g*9+2]*qz + T[g*3+0];
  py = R[g*9+3]*qx + R[g*9+4]*qy + R[g*9+5]*qz + T[g*3+1];
  pz = R[g*9+6]*qx + R[g*9+7]*qy + R[g*9+8]*qz + T[g*3+2];
  posp[i*3+0]=px; posp[i*3+1]=py; posp[i*3+2]=pz;
  float is = 1.0f/sigma[i];
  target[i*3+0]=(pos[i*3+0]-px)*is;
  target[i*3+1]=(pos[i*3+1]-py)*is;
  target[i*3+2]=(pos[i*3+2]-pz)*is;
}

// ---------------- prep (bf16 conversions, small weight fusions) ----------------

__global__ void k_cvt_x(const float* __restrict__ x, u16* __restrict__ xb){
  size_t i = ((size_t)blockIdx.x*256 + threadIdx.x)*4;
  float4 v = *(const float4*)(x+i);
  u16 o0=f2bf(v.x), o1=f2bf(v.y), o2=f2bf(v.z), o3=f2bf(v.w);
  xb[i+0]=o0; xb[i+1]=o1; xb[i+2]=o2; xb[i+3]=o3;
}

// Wt[n][k] = bf16(W[k][n])
__global__ void k_wt(const float* __restrict__ W, u16* __restrict__ Wt){
  int idx = blockIdx.x*256+threadIdx.x;   // 65536
  int k = idx>>8, n = idx&255;
  Wt[n*256+k] = f2bf(W[k*256+n]);
}

// wmg = W_msg @ w_gate  (f32, exact path for coef)
__global__ void k_wmg(const float* __restrict__ Wmsg, const float* __restrict__ wgate,
                      float* __restrict__ wmg){
  int k = threadIdx.x;
  float s=0.f;
  for(int j=0;j<256;j++) s += Wmsg[k*256+j]*wgate[j];
  wmg[k]=s;
}

__global__ void k_wpeff(const float* __restrict__ Wp1, float* __restrict__ Wpe){
  int idx = blockIdx.x*256+threadIdx.x;   // 65536
  Wpe[idx] = Wp1[idx] + Wp1[idx + 65536];
}

// gn[i] = dot(x[i,:], wmg)   (one wave per node)
__global__ void k_gn(const float* __restrict__ x, const float* __restrict__ wmg,
                     float* __restrict__ gn){
  int wave = threadIdx.x>>6, lane = threadIdx.x&63;
  int i = blockIdx.x*4 + wave;
  const float4* xr = (const float4*)(x + (size_t)i*256);
  const float4* wr = (const float4*)wmg;
  float4 a = xr[lane]; float4 b = wr[lane];
  float s = a.x*b.x + a.y*b.y + a.z*b.z + a.w*b.w;
  #pragma unroll
  for(int o=32;o;o>>=1) s += __shfl_down(s,o);
  if(lane==0) gn[i]=s;
}

// ---------------- bf16 MFMA GEMM: [NN,256] @ [256,256] ----------------
// MODE 0: out_b = bf16(acc)                         (xm)
// MODE 1: out_b = bf16(silu(acc + extra[m][n]))     (xl, extra=agg)
// MODE 2: out_b = bf16(silu(acc + bias[n]))         (h1)
// MODE 3: atomicAdd(xg[n2g[m]][n], acc + bias[n])   (xl2 -> seg_sum)
template<int MODE>
__global__ __launch_bounds__(256) void gemm256(const u16* __restrict__ A, const u16* __restrict__ Wt,
                        const float* __restrict__ bias, const float* __restrict__ extra,
                        const int* __restrict__ n2g,
                        u16* __restrict__ outb, float* __restrict__ outf){
  int wave = threadIdx.x>>6, lane = threadIdx.x&63;
  int tile = blockIdx.x*4 + wave;        // 16-row tile, 4096 tiles
  int m0 = tile*16;
  int lr = lane&15, lk = (lane>>4)*8;
  f32x4 acc[16];
  #pragma unroll
  for(int n=0;n<16;n++) acc[n]=(f32x4){0.f,0.f,0.f,0.f};
  #pragma unroll
  for(int k0=0;k0<256;k0+=32){
    short8 a = *(const short8*)(A + (size_t)(m0+lr)*256 + k0 + lk);
    #pragma unroll
    for(int n=0;n<16;n++){
      short8 b = *(const short8*)(Wt + (size_t)(n*16+lr)*256 + k0 + lk);
      acc[n] = __builtin_amdgcn_mfma_f32_16x16x32_bf16(a,b,acc[n],0,0,0);
    }
  }
  int rbase = m0 + ((lane>>4)<<2);
  #pragma unroll
  for(int j=0;j<4;j++){
    int r = rbase + j;
    int gg = 0;
    if(MODE==3) gg = n2g[r];
    #pragma unroll
    for(int n=0;n<16;n++){
      int c = n*16 + lr;
      float v = acc[n][j];
      if(MODE==0){ outb[(size_t)r*256+c] = f2bf(v); }
      else if(MODE==1){ v += extra[(size_t)r*256+c]; outb[(size_t)r*256+c]=f2bf(silu_f(v)); }
      else if(MODE==2){ v += bias[c]; outb[(size_t)r*256+c]=f2bf(silu_f(v)); }
      else { v += bias[c]; atomicAdd(&outf[(size_t)gg*256+c], v); }
    }
  }
}

// ---------------- edge kernels ----------------

__global__ void k_eagg(const u16* __restrict__ xmb, const int* __restrict__ ei,
                       float* __restrict__ agg){
  int t = threadIdx.x;
  int e0 = blockIdx.x*8;
  #pragma unroll
  for(int q=0;q<8;q++){
    int e = e0+q;
    int r = ei[e], c = ei[NE+e];
    float v = bf2f(xmb[(size_t)r*256+t]);
    atomicAdd(&agg[(size_t)c*256+t], v);
  }
}

__global__ void k_edelta(const float* __restrict__ posp, const float* __restrict__ gn,
                         const int* __restrict__ ei, float* __restrict__ delta){
  int e = blockIdx.x*256+threadIdx.x; if(e>=NE) return;
  int r=ei[e], c=ei[NE+e];
  float coef = silu_f(gn[r]);
  float dx=(posp[r*3+0]-posp[c*3+0])*coef;
  float dy=(posp[r*3+1]-posp[c*3+1])*coef;
  float dz=(posp[r*3+2]-posp[c*3+2])*coef;
  atomicAdd(&delta[c*3+0],dx);
  atomicAdd(&delta[c*3+1],dy);
  atomicAdd(&delta[c*3+2],dz);
}

__global__ void k_loss(const float* __restrict__ delta, const float* __restrict__ target,
                       const float* __restrict__ sigma, float* __restrict__ accum){
  int i = blockIdx.x*256+threadIdx.x;
  float s=0.f;
  if(i<NN){
    float is=1.f/sigma[i];
    #pragma unroll
    for(int d=0;d<3;d++){
      float df = delta[i*3+d]*is - target[i*3+d];
      s += df*df;
    }
  }
  #pragma unroll
  for(int o=32;o;o>>=1) s += __shfl_down(s,o);
  if((threadIdx.x&63)==0) atomicAdd(&accum[0], s);
}

// ---------------- head ----------------

__global__ void k_head1(const float* __restrict__ xg, const float* __restrict__ Wpe,
                        const float* __restrict__ bp1, float* __restrict__ hh){
  __shared__ float xs[256];
  int g = blockIdx.x, t = threadIdx.x;
  xs[t] = xg[(size_t)g*256+t];
  __syncthreads();
  float s = bp1[t];
  for(int k=0;k<256;k++) s += xs[k]*Wpe[k*256+t];
  hh[(size_t)g*256+t] = silu_f(s);
}

__global__ void k_head2(const float* __restrict__ hh, const float* __restrict__ Wp2,
                        const float* __restrict__ bp2, const int* __restrict__ nl,
                        float* __restrict__ accum){
  __shared__ float hs[256];
  int g = blockIdx.x, t = threadIdx.x;  // 64 threads
  for(int k=t;k<256;k+=64) hs[k]=hh[(size_t)g*256+k];
  __syncthreads();
  float logit = -1e30f;
  if(t<NL){
    float s = bp2[t];
    for(int k=0;k<256;k++) s += hs[k]*Wp2[k*NL+t];
    logit = s;
  }
  float mx = logit;
  #pragma unroll
  for(int o=32;o;o>>=1) mx = fmaxf(mx, __shfl_xor(mx,o));
  float ex = (t<NL)? __expf(logit-mx) : 0.f;
  float se = ex;
  #pragma unroll
  for(int o=32;o;o>>=1) se += __shfl_xor(se,o);
  float lse = logf(se)+mx;
  float lsel = __shfl(logit, nl[g]);
  if(t==0) atomicAdd(&accum[1], lse - lsel);
}

__global__ void k_final(const float* __restrict__ accum, float* __restrict__ out){
  out[0] = accum[0]/(float)NG;
  out[1] = accum[1]/(float)NG;
}

// ---------------- launcher ----------------

extern "C" void kernel_launch(void* const* d_in, const int* in_sizes, int n_in,
                              void* d_out, int out_size, void* d_ws, size_t ws_size,
                              hipStream_t stream){
  (void)in_sizes; (void)n_in; (void)out_size; (void)ws_size;
  const float* x      = (const float*)d_in[0];
  const float* pos    = (const float*)d_in[1];
  const float* noise  = (const float*)d_in[2];
  const int*   n2g    = (const int*)d_in[3];
  const int*   ei     = (const int*)d_in[4];
  const int*   nl     = (const int*)d_in[5];
  const float* W_node = (const float*)d_in[6];
  const float* W_msg  = (const float*)d_in[7];
  const float* w_gate = (const float*)d_in[8];
  const float* Wd1    = (const float*)d_in[9];
  const float* bd1    = (const float*)d_in[10];
  const float* Wd2    = (const float*)d_in[11];
  const float* bd2    = (const float*)d_in[12];
  const float* Wp1    = (const float*)d_in[17];
  const float* bp1    = (const float*)d_in[18];
  const float* Wp2    = (const float*)d_in[19];
  const float* bp2    = (const float*)d_in[20];
  float* out = (float*)d_out;

  char* w = (char*)d_ws;
  size_t off = 0;
  auto alloc = [&](size_t bytes)->void*{
    void* p = w + off;
    off += (bytes + 255) & ~(size_t)255;
    return p;
  };

  // --- zero region (one memset covers all) ---
  size_t zstart = off;
  float* agg     = (float*)alloc((size_t)NN*HD*4);   // 64MB
  float* xg      = (float*)alloc((size_t)NG*HD*4);   // 2MB
  float* delta   = (float*)alloc((size_t)NN*3*4);
  float* sum_pos = (float*)alloc((size_t)NG*3*4);
  float* sum_pp  = (float*)alloc((size_t)NG*3*4);
  float* cnt     = (float*)alloc((size_t)NG*4);
  float* Hm      = (float*)alloc((size_t)NG*9*4);
  float* accum   = (float*)alloc(2*4);
  size_t zend = off;

  // --- other buffers ---
  u16*  xb   = (u16*)alloc((size_t)NN*HD*2);   // bf16 x
  u16*  xmb  = (u16*)alloc((size_t)NN*HD*2);   // bf16 xm ; later reused as h1
  u16*  xlb  = (u16*)alloc((size_t)NN*HD*2);   // bf16 xl
  float* sigma  = (float*)alloc((size_t)NN*4);
  float* ppin   = (float*)alloc((size_t)NN*3*4);
  float* posp   = (float*)alloc((size_t)NN*3*4);
  float* target = (float*)alloc((size_t)NN*3*4);
  float* gn     = (float*)alloc((size_t)NN*4);
  float* center = (float*)alloc((size_t)NG*3*4);
  float* pcenter= (float*)alloc((size_t)NG*3*4);
  float* Rm     = (float*)alloc((size_t)NG*9*4);
  float* Tm     = (float*)alloc((size_t)NG*3*4);
  u16*  wt_msg  = (u16*)alloc((size_t)HD*HD*2);
  u16*  wt_node = (u16*)alloc((size_t)HD*HD*2);
  u16*  wt_d1   = (u16*)alloc((size_t)HD*HD*2);
  u16*  wt_d2   = (u16*)alloc((size_t)HD*HD*2);
  float* wmg    = (float*)alloc((size_t)HD*4);
  float* wpe    = (float*)alloc((size_t)HD*HD*4);
  float* hh     = (float*)alloc((size_t)NG*HD*4);

  hipMemsetAsync(w+zstart, 0, zend-zstart, stream);

  // Kabsch path
  k_sigma <<<NN/256,256,0,stream>>>(pos,noise,n2g,nl,sigma,ppin,sum_pos,sum_pp,cnt);
  k_center<<<NG/256,256,0,stream>>>(sum_pos,sum_pp,cnt,center,pcenter);
  k_H     <<<NN/256,256,0,stream>>>(pos,ppin,n2g,center,pcenter,Hm);
  k_polar <<<NG/256,256,0,stream>>>(Hm,center,pcenter,Rm,Tm);
  k_posp  <<<NN/256,256,0,stream>>>(ppin,pos,sigma,n2g,Rm,Tm,posp,target);

  // prep
  k_cvt_x <<<(NN*HD/4)/256,256,0,stream>>>(x,xb);
  k_wt    <<<(HD*HD)/256,256,0,stream>>>(W_msg ,wt_msg);
  k_wt    <<<(HD*HD)/256,256,0,stream>>>(W_node,wt_node);
  k_wt    <<<(HD*HD)/256,256,0,stream>>>(Wd1   ,wt_d1);
  k_wt    <<<(HD*HD)/256,256,0,stream>>>(Wd2   ,wt_d2);
  k_wmg   <<<1,256,0,stream>>>(W_msg,w_gate,wmg);
  k_wpeff <<<(HD*HD)/256,256,0,stream>>>(Wp1,wpe);
  k_gn    <<<NN/4,256,0,stream>>>(x,wmg,gn);

  // GNN + decoders
  gemm256<0><<<NN/64,256,0,stream>>>(xb ,wt_msg ,nullptr,nullptr,nullptr,xmb,nullptr); // xm
  k_eagg  <<<NE/8,256,0,stream>>>(xmb,ei,agg);                                          // agg
  gemm256<1><<<NN/64,256,0,stream>>>(xb ,wt_node,nullptr,agg    ,nullptr,xlb,nullptr); // xl
  gemm256<2><<<NN/64,256,0,stream>>>(xlb,wt_d1  ,bd1    ,nullptr,nullptr,xmb,nullptr); // h1 (reuse xmb)
  gemm256<3><<<NN/64,256,0,stream>>>(xmb,wt_d2  ,bd2    ,nullptr,n2g    ,nullptr,xg);  // xl2 -> xg

  // position branch + loss
  k_edelta<<<NE/256,256,0,stream>>>(posp,gn,ei,delta);
  k_loss  <<<NN/256,256,0,stream>>>(delta,target,sigma,accum);

  // classifier head + ce
  k_head1 <<<NG,256,0,stream>>>(xg,wpe,bp1,hh);
  k_head2 <<<NG,64,0,stream>>>(hh,Wp2,bp2,nl,accum);

  k_final <<<1,1,0,stream>>>(accum,out);
}

// Round 2
// 623.336 us; speedup vs baseline: 2.0391x; 2.0391x over previous
//
#include <hip/hip_runtime.h>
#include <math.h>

#define NN 65536   // nodes
#define NE 524288  // edges
#define NG 2048    // graphs
#define HD 256     // hidden
#define NL 50      // noise levels

typedef unsigned short u16;
typedef __attribute__((ext_vector_type(8))) short short8;
typedef __attribute__((ext_vector_type(4))) float f32x4;
typedef __attribute__((ext_vector_type(4))) unsigned short us4;

__device__ __forceinline__ float bf2f(u16 h){
  union{unsigned int u; float f;} v; v.u = ((unsigned int)h)<<16; return v.f;
}
__device__ __forceinline__ u16 f2bf(float f){
  union{float f; unsigned int u;} v; v.f=f;
  return (u16)((v.u + 0x7FFFu + ((v.u>>16)&1u))>>16);
}
__device__ __forceinline__ float silu_f(float v){ return v/(1.0f+__expf(-v)); }

// ---------------- graph boundaries (n2g is sorted) ----------------
// gstart[g] = first node index i with n2g[i] >= g ; gstart[NG] = NN
__global__ void k_gb(const int* __restrict__ n2g, int* __restrict__ gstart){
  int i = blockIdx.x*256 + threadIdx.x;
  if(i>NN) return;
  int cur  = (i<NN)? n2g[i] : NG;
  int prev = (i==0)? -1 : n2g[i-1];
  for(int g=prev+1; g<=cur; ++g) gstart[g]=i;
}

__global__ void k_sigg(const int* __restrict__ nl, float* __restrict__ sigg){
  int g = blockIdx.x*256+threadIdx.x; if(g>=NG) return;
  const double L0 =  2.3025850929940456840;  // ln 10
  const double L1 = -4.6051701859880913680;  // ln 0.01
  sigg[g] = (float)exp(L0 + (double)nl[g]*(L1-L0)/49.0);
}

// ---------------- Kabsch path ----------------

__global__ void k_perturb(const float* __restrict__ pos, const float* __restrict__ noise,
                          const int* __restrict__ n2g, const float* __restrict__ sigg,
                          float* __restrict__ ppin,
                          float* __restrict__ sum_pos, float* __restrict__ sum_pp){
  int i = blockIdx.x*256 + threadIdx.x;
  if(i>=NN) return;
  int g = n2g[i];
  float sg = sigg[g];
  float px=pos[i*3+0], py=pos[i*3+1], pz=pos[i*3+2];
  float qx=px+noise[i*3+0]*sg, qy=py+noise[i*3+1]*sg, qz=pz+noise[i*3+2]*sg;
  ppin[i*3+0]=qx; ppin[i*3+1]=qy; ppin[i*3+2]=qz;
  atomicAdd(&sum_pos[g*3+0],px); atomicAdd(&sum_pos[g*3+1],py); atomicAdd(&sum_pos[g*3+2],pz);
  atomicAdd(&sum_pp [g*3+0],qx); atomicAdd(&sum_pp [g*3+1],qy); atomicAdd(&sum_pp [g*3+2],qz);
}

__global__ void k_center(const float* __restrict__ sum_pos, const float* __restrict__ sum_pp,
                         const int* __restrict__ gstart,
                         float* __restrict__ center, float* __restrict__ pcenter){
  int g = blockIdx.x*256+threadIdx.x; if(g>=NG) return;
  float c = fmaxf((float)(gstart[g+1]-gstart[g]),1.0f);
  #pragma unroll
  for(int d=0;d<3;d++){ center[g*3+d]=sum_pos[g*3+d]/c; pcenter[g*3+d]=sum_pp[g*3+d]/c; }
}

__global__ void k_H(const float* __restrict__ pos, const float* __restrict__ ppin,
                    const int* __restrict__ n2g, const float* __restrict__ center,
                    const float* __restrict__ pcenter, float* __restrict__ Hm){
  int i = blockIdx.x*256+threadIdx.x; if(i>=NN) return;
  int g=n2g[i];
  float a0=ppin[i*3+0]-pcenter[g*3+0];
  float a1=ppin[i*3+1]-pcenter[g*3+1];
  float a2=ppin[i*3+2]-pcenter[g*3+2];
  float b0=pos[i*3+0]-center[g*3+0];
  float b1=pos[i*3+1]-center[g*3+1];
  float b2=pos[i*3+2]-center[g*3+2];
  atomicAdd(&Hm[g*9+0],a0*b0); atomicAdd(&Hm[g*9+1],a0*b1); atomicAdd(&Hm[g*9+2],a0*b2);
  atomicAdd(&Hm[g*9+3],a1*b0); atomicAdd(&Hm[g*9+4],a1*b1); atomicAdd(&Hm[g*9+5],a1*b2);
  atomicAdd(&Hm[g*9+6],a2*b0); atomicAdd(&Hm[g*9+7],a2*b1); atomicAdd(&Hm[g*9+8],a2*b2);
}

// R = polar orthogonal factor of H^T ( == V U^T with H = U S V^T ), Newton iteration.
__global__ void k_polar(const float* __restrict__ Hm, const float* __restrict__ center,
                        const float* __restrict__ pcenter,
                        float* __restrict__ R, float* __restrict__ T){
  int g = blockIdx.x*256+threadIdx.x; if(g>=NG) return;
  float X[3][3];
  #pragma unroll
  for(int r=0;r<3;r++)
    #pragma unroll
    for(int c=0;c<3;c++) X[r][c]=Hm[g*9 + c*3 + r];   // X = H^T
  float nf=0.f;
  #pragma unroll
  for(int r=0;r<3;r++) for(int c=0;c<3;c++) nf += X[r][c]*X[r][c];
  nf = sqrtf(nf);
  if(nf < 1e-20f){
    #pragma unroll
    for(int r=0;r<3;r++) for(int c=0;c<3;c++) X[r][c]=(r==c)?1.f:0.f;
  } else {
    float s0=1.f/nf;
    #pragma unroll
    for(int r=0;r<3;r++) for(int c=0;c<3;c++) X[r][c]*=s0;
    for(int it=0; it<30; ++it){
      float a=X[0][0],b=X[0][1],c=X[0][2];
      float d=X[1][0],e=X[1][1],f=X[1][2];
      float gg=X[2][0],h=X[2][1],ii=X[2][2];
      float A_= e*ii-f*h, B_=-(d*ii-f*gg), C_= d*h-e*gg;
      float D_=-(b*ii-c*h), E_= a*ii-c*gg, F_=-(a*h-b*gg);
      float G_= b*f-c*e,  H_=-(a*f-c*d),  I_= a*e-b*d;
      float det = a*A_ + b*B_ + c*C_;
      if(!(fabsf(det) > 1e-25f)){
        if(it==0){
          for(int r=0;r<3;r++) for(int cc=0;cc<3;cc++) X[r][cc]=(r==cc)?1.f:0.f;
        }
        break;
      }
      float si = 0.5f/det;
      float Y00=0.5f*a + si*A_, Y01=0.5f*b + si*B_, Y02=0.5f*c + si*C_;
      float Y10=0.5f*d + si*D_, Y11=0.5f*e + si*E_, Y12=0.5f*f + si*F_;
      float Y20=0.5f*gg+ si*G_, Y21=0.5f*h + si*H_, Y22=0.5f*ii+ si*I_;
      X[0][0]=Y00; X[0][1]=Y01; X[0][2]=Y02;
      X[1][0]=Y10; X[1][1]=Y11; X[1][2]=Y12;
      X[2][0]=Y20; X[2][1]=Y21; X[2][2]=Y22;
    }
  }
  float pcx=pcenter[g*3+0], pcy=pcenter[g*3+1], pcz=pcenter[g*3+2];
  #pragma unroll
  for(int r=0;r<3;r++){
    T[g*3+r] = center[g*3+r] - (X[r][0]*pcx + X[r][1]*pcy + X[r][2]*pcz);
    #pragma unroll
    for(int c=0;c<3;c++) R[g*9+r*3+c]=X[r][c];
  }
}

__global__ void k_posp(const float* __restrict__ ppin, const float* __restrict__ pos,
                       const float* __restrict__ sigg, const int* __restrict__ n2g,
                       const float* __restrict__ R, const float* __restrict__ T,
                       float* __restrict__ posp, float* __restrict__ target){
  int i = blockIdx.x*256+threadIdx.x; if(i>=NN) return;
  int g=n2g[i];
  float qx=ppin[i*3+0], qy=ppin[i*3+1], qz=ppin[i*3+2];
  float px,py,pz;
  px = R[g*9+0]*qx + R[g*9+1]*qy + R[g*9+2]*qz + T[g*3+0];
  py = R[g*9+3]*qx + R[g*9+4]*qy + R[g*9+5]*qz + T[g*3+1];
  pz = R[g*9+6]*qx + R[g*9+7]*qy + R[g*9+8]*qz + T[g*3+2];
  posp[i*3+0]=px; posp[i*3+1]=py; posp[i*3+2]=pz;
  float is = 1.0f/sigg[g];
  target[i*3+0]=(pos[i*3+0]-px)*is;
  target[i*3+1]=(pos[i*3+1]-py)*is;
  target[i*3+2]=(pos[i*3+2]-pz)*is;
}

// ---------------- prep ----------------

// wmg = W_msg @ w_gate  (f32 exact)
__global__ void k_wmg(const float* __restrict__ Wmsg, const float* __restrict__ wgate,
                      float* __restrict__ wmg){
  int k = threadIdx.x;
  float s=0.f;
  for(int j=0;j<256;j++) s += Wmsg[k*256+j]*wgate[j];
  wmg[k]=s;
}

// fused: xb = bf16(x), cf[i] = silu(dot(x[i], wmg))   (one wave per row)
__global__ void k_prep(const float* __restrict__ x, const float* __restrict__ wmg,
                       u16* __restrict__ xb, float* __restrict__ cf){
  int wave = threadIdx.x>>6, lane = threadIdx.x&63;
  int i = blockIdx.x*4 + wave;
  float4 a = ((const float4*)(x + (size_t)i*256))[lane];
  float4 b = ((const float4*)wmg)[lane];
  float s = a.x*b.x + a.y*b.y + a.z*b.z + a.w*b.w;
  us4 o; o.x=f2bf(a.x); o.y=f2bf(a.y); o.z=f2bf(a.z); o.w=f2bf(a.w);
  *(us4*)(xb + (size_t)i*256 + lane*4) = o;
  #pragma unroll
  for(int of=32;of;of>>=1) s += __shfl_down(s,of);
  if(lane==0) cf[i]=silu_f(s);
}

// Wt[n][k] = bf16(W[k][n])
__global__ void k_wt(const float* __restrict__ W, u16* __restrict__ Wt){
  int idx = blockIdx.x*256+threadIdx.x;   // 65536
  int k = idx>>8, n = idx&255;
  Wt[n*256+k] = f2bf(W[k*256+n]);
}

// plain f32 -> bf16 copy (same layout)
__global__ void k_cvtw(const float* __restrict__ W, u16* __restrict__ Wb, int n){
  int idx = blockIdx.x*256+threadIdx.x; if(idx>=n) return;
  Wb[idx] = f2bf(W[idx]);
}

// wpeb = bf16(Wp1[:256] + Wp1[256:])   (xg_ori == xg_noise)
__global__ void k_wpe(const float* __restrict__ Wp1, u16* __restrict__ Wpe){
  int idx = blockIdx.x*256+threadIdx.x;   // 65536
  Wpe[idx] = f2bf(Wp1[idx] + Wp1[idx + 65536]);
}

// ---------------- CSR build (counting sort of edges by destination) ----------------

__global__ void k_count(const int* __restrict__ ei, int* __restrict__ cnt_e){
  int e = blockIdx.x*256+threadIdx.x; if(e>=NE) return;
  atomicAdd(&cnt_e[ei[NE+e]],1);
}

__global__ void k_scan_a(const int* __restrict__ cnt_e, int* __restrict__ start,
                         int* __restrict__ bsum){
  __shared__ int sh[256];
  int b=blockIdx.x, t=threadIdx.x, i=b*256+t;
  int v = cnt_e[i]; sh[t]=v; __syncthreads();
  #pragma unroll
  for(int o=1;o<256;o<<=1){
    int u = (t>=o)? sh[t-o]:0; __syncthreads(); sh[t]+=u; __syncthreads();
  }
  start[i] = sh[t]-v;
  if(t==255) bsum[b]=sh[255];
}

__global__ void k_scan_b(int* __restrict__ bsum){
  __shared__ int sh[256];
  int t=threadIdx.x; int v=bsum[t]; sh[t]=v; __syncthreads();
  #pragma unroll
  for(int o=1;o<256;o<<=1){
    int u=(t>=o)?sh[t-o]:0; __syncthreads(); sh[t]+=u; __syncthreads();
  }
  bsum[t]=sh[t]-v;
}

__global__ void k_scan_c(int* __restrict__ start, const int* __restrict__ bsum,
                         int* __restrict__ cursor){
  int b=blockIdx.x, i=b*256+threadIdx.x;
  int v = start[i]+bsum[b];
  start[i]=v; cursor[i]=v;
  if(i==0) start[NN]=NE;
}

__global__ void k_scatter(const int* __restrict__ ei, int* __restrict__ cursor,
                          int* __restrict__ elist){
  int e = blockIdx.x*256+threadIdx.x; if(e>=NE) return;
  int c = ei[NE+e];
  int p = atomicAdd(&cursor[c],1);
  elist[p] = ei[e];
}

// ---------------- neighbor gather: xs[c] = sum_{r in N(c)} xb[r] ----------------

__global__ void k_gather(const u16* __restrict__ xb, const int* __restrict__ start,
                         const int* __restrict__ elist, u16* __restrict__ xsb){
  int c = blockIdx.x, t = threadIdx.x;
  int s0=start[c], s1=start[c+1];
  float acc=0.f;
  int e=s0;
  for(; e+1<s1; e+=2){
    int r0=elist[e], r1=elist[e+1];
    acc += bf2f(xb[(size_t)r0*256+t]) + bf2f(xb[(size_t)r1*256+t]);
  }
  if(e<s1) acc += bf2f(xb[(size_t)elist[e]*256+t]);
  xsb[(size_t)c*256+t] = f2bf(acc);
}

// ---------------- MFMA GEMM: out = bf16(silu(A1@B1^T [+ A2@B2^T] [+ bias])) ----------------
template<int DUAL>
__global__ __launch_bounds__(256) void gemmA(const u16* __restrict__ A1, const u16* __restrict__ A2,
                       const u16* __restrict__ B1, const u16* __restrict__ B2,
                       const float* __restrict__ bias, u16* __restrict__ outb){
  int wave = threadIdx.x>>6, lane = threadIdx.x&63;
  int tile = blockIdx.x*4 + wave;
  int m0 = tile*16;
  int lr = lane&15, lk = (lane>>4)*8;
  f32x4 acc[16];
  #pragma unroll
  for(int n=0;n<16;n++) acc[n]=(f32x4){0.f,0.f,0.f,0.f};
  #pragma unroll
  for(int k0=0;k0<256;k0+=32){
    short8 a1 = *(const short8*)(A1 + (size_t)(m0+lr)*256 + k0 + lk);
    #pragma unroll
    for(int n=0;n<16;n++){
      short8 b = *(const short8*)(B1 + (size_t)(n*16+lr)*256 + k0 + lk);
      acc[n] = __builtin_amdgcn_mfma_f32_16x16x32_bf16(a1,b,acc[n],0,0,0);
    }
    if(DUAL){
      short8 a2 = *(const short8*)(A2 + (size_t)(m0+lr)*256 + k0 + lk);
      #pragma unroll
      for(int n=0;n<16;n++){
        short8 b = *(const short8*)(B2 + (size_t)(n*16+lr)*256 + k0 + lk);
        acc[n] = __builtin_amdgcn_mfma_f32_16x16x32_bf16(a2,b,acc[n],0,0,0);
      }
    }
  }
  int rbase = m0 + ((lane>>4)<<2);
  #pragma unroll
  for(int j=0;j<4;j++){
    int r = rbase + j;
    #pragma unroll
    for(int n=0;n<16;n++){
      int c = n*16 + lr;
      float v = acc[n][j];
      if(!DUAL) v += bias[c];
      outb[(size_t)r*256+c]=f2bf(silu_f(v));
    }
  }
}

// ---------------- per-graph seg-sum of h1 (contiguous rows, no atomics) ----------------

__global__ void k_sg(const u16* __restrict__ h1b, const int* __restrict__ gstart,
                     float* __restrict__ sg){
  int g = blockIdx.x, t = threadIdx.x;
  int s0=gstart[g], s1=gstart[g+1];
  float acc=0.f;
  for(int i=s0;i<s1;i++) acc += bf2f(h1b[(size_t)i*256+t]);
  sg[(size_t)g*256+t]=acc;
}

// ---------------- fused head: xg = sg@Wd2 + cnt*bd2 ; h=silu(xg@Wpe+bp1) ; ce ----------------

__global__ __launch_bounds__(256) void k_head(const float* __restrict__ sg, const int* __restrict__ gstart,
                       const float* __restrict__ bd2, const u16* __restrict__ wd2b,
                       const u16* __restrict__ wpeb, const float* __restrict__ bp1,
                       const u16* __restrict__ wp2b, const float* __restrict__ bp2,
                       const int* __restrict__ nl, float* __restrict__ accum){
  __shared__ float sh[256];
  __shared__ float xg[256];
  __shared__ float hh[256];
  int g = blockIdx.x, t = threadIdx.x;
  sh[t] = sg[(size_t)g*256+t];
  float cntg = (float)(gstart[g+1]-gstart[g]);
  __syncthreads();
  {
    float s = cntg*bd2[t];
    for(int k=0;k<256;k++) s += sh[k]*bf2f(wd2b[k*256+t]);
    xg[t] = s;
  }
  __syncthreads();
  {
    float s = bp1[t];
    for(int k=0;k<256;k++) s += xg[k]*bf2f(wpeb[k*256+t]);
    hh[t] = silu_f(s);
  }
  __syncthreads();
  if(t<64){
    float logit = -1e30f;
    if(t<NL){
      float s = bp2[t];
      for(int k=0;k<256;k++) s += hh[k]*bf2f(wp2b[k*NL+t]);
      logit = s;
    }
    float mx = logit;
    #pragma unroll
    for(int o=32;o;o>>=1) mx = fmaxf(mx, __shfl_xor(mx,o));
    float ex = (t<NL)? __expf(logit-mx) : 0.f;
    float se = ex;
    #pragma unroll
    for(int o=32;o;o>>=1) se += __shfl_xor(se,o);
    float lse = logf(se)+mx;
    float lsel = __shfl(logit, nl[g]);
    if(t==0) atomicAdd(&accum[1], lse - lsel);
  }
}

// ---------------- fused edge-delta + denoise loss (CSR, per node) ----------------

__global__ void k_eloss(const int* __restrict__ start, const int* __restrict__ elist,
                        const float* __restrict__ posp, const float* __restrict__ cf,
                        const float* __restrict__ target, const float* __restrict__ sigg,
                        const int* __restrict__ n2g, float* __restrict__ accum){
  int i = blockIdx.x*256+threadIdx.x;
  float s=0.f;
  if(i<NN){
    int s0=start[i], s1=start[i+1];
    float px=posp[i*3+0], py=posp[i*3+1], pz=posp[i*3+2];
    float dx=0.f, dy=0.f, dz=0.f;
    for(int e=s0;e<s1;e++){
      int r=elist[e];
      float c=cf[r];
      dx += (posp[r*3+0]-px)*c;
      dy += (posp[r*3+1]-py)*c;
      dz += (posp[r*3+2]-pz)*c;
    }
    float is = 1.f/sigg[n2g[i]];
    float d0 = dx*is - target[i*3+0];
    float d1 = dy*is - target[i*3+1];
    float d2 = dz*is - target[i*3+2];
    s = d0*d0+d1*d1+d2*d2;
  }
  #pragma unroll
  for(int o=32;o;o>>=1) s += __shfl_down(s,o);
  if((threadIdx.x&63)==0) atomicAdd(&accum[0], s);
}

__global__ void k_final(const float* __restrict__ accum, float* __restrict__ out){
  out[0] = accum[0]/(float)NG;
  out[1] = accum[1]/(float)NG;
}

// ---------------- launcher ----------------

extern "C" void kernel_launch(void* const* d_in, const int* in_sizes, int n_in,
                              void* d_out, int out_size, void* d_ws, size_t ws_size,
                              hipStream_t stream){
  (void)in_sizes; (void)n_in; (void)out_size; (void)ws_size;
  const float* x      = (const float*)d_in[0];
  const float* pos    = (const float*)d_in[1];
  const float* noise  = (const float*)d_in[2];
  const int*   n2g    = (const int*)d_in[3];
  const int*   ei     = (const int*)d_in[4];
  const int*   nl     = (const int*)d_in[5];
  const float* W_node = (const float*)d_in[6];
  const float* W_msg  = (const float*)d_in[7];
  const float* w_gate = (const float*)d_in[8];
  const float* Wd1    = (const float*)d_in[9];
  const float* bd1    = (const float*)d_in[10];
  const float* Wd2    = (const float*)d_in[11];
  const float* bd2    = (const float*)d_in[12];
  const float* Wp1    = (const float*)d_in[17];
  const float* bp1    = (const float*)d_in[18];
  const float* Wp2    = (const float*)d_in[19];
  const float* bp2    = (const float*)d_in[20];
  float* out = (float*)d_out;

  char* w = (char*)d_ws;
  size_t off = 0;
  auto alloc = [&](size_t bytes)->void*{
    void* p = w + off;
    off += (bytes + 255) & ~(size_t)255;
    return p;
  };

  // --- zeroed region ---
  size_t zstart = off;
  int*   cnt_e   = (int*)alloc((size_t)NN*4);
  float* sum_pos = (float*)alloc((size_t)NG*3*4);
  float* sum_pp  = (float*)alloc((size_t)NG*3*4);
  float* Hm      = (float*)alloc((size_t)NG*9*4);
  float* accum   = (float*)alloc(2*4);
  size_t zend = off;

  // --- other buffers ---
  u16*  xb   = (u16*)alloc((size_t)NN*HD*2);
  u16*  xsb  = (u16*)alloc((size_t)NN*HD*2);
  u16*  xlb  = (u16*)alloc((size_t)NN*HD*2);
  u16*  h1b  = (u16*)alloc((size_t)NN*HD*2);
  float* sg     = (float*)alloc((size_t)NG*HD*4);
  float* sigg   = (float*)alloc((size_t)NG*4);
  float* ppin   = (float*)alloc((size_t)NN*3*4);
  float* posp   = (float*)alloc((size_t)NN*3*4);
  float* target = (float*)alloc((size_t)NN*3*4);
  float* cf     = (float*)alloc((size_t)NN*4);
  float* center = (float*)alloc((size_t)NG*3*4);
  float* pcenter= (float*)alloc((size_t)NG*3*4);
  float* Rm     = (float*)alloc((size_t)NG*9*4);
  float* Tm     = (float*)alloc((size_t)NG*3*4);
  int*  gstart  = (int*)alloc((size_t)(NG+1)*4);
  int*  start   = (int*)alloc((size_t)(NN+1)*4);
  int*  cursor  = (int*)alloc((size_t)NN*4);
  int*  bsum    = (int*)alloc((size_t)256*4);
  int*  elist   = (int*)alloc((size_t)NE*4);
  u16*  wt_node = (u16*)alloc((size_t)HD*HD*2);
  u16*  wt_msg  = (u16*)alloc((size_t)HD*HD*2);
  u16*  wt_d1   = (u16*)alloc((size_t)HD*HD*2);
  u16*  wd2b    = (u16*)alloc((size_t)HD*HD*2);
  u16*  wpeb    = (u16*)alloc((size_t)HD*HD*2);
  u16*  wp2b    = (u16*)alloc((size_t)HD*NL*2);
  float* wmg    = (float*)alloc((size_t)HD*4);

  hipMemsetAsync(w+zstart, 0, zend-zstart, stream);

  // graph structure
  k_gb    <<<(NN+256)/256,256,0,stream>>>(n2g,gstart);
  k_sigg  <<<NG/256,256,0,stream>>>(nl,sigg);

  // Kabsch path
  k_perturb<<<NN/256,256,0,stream>>>(pos,noise,n2g,sigg,ppin,sum_pos,sum_pp);
  k_center <<<NG/256,256,0,stream>>>(sum_pos,sum_pp,gstart,center,pcenter);
  k_H      <<<NN/256,256,0,stream>>>(pos,ppin,n2g,center,pcenter,Hm);
  k_polar  <<<NG/256,256,0,stream>>>(Hm,center,pcenter,Rm,Tm);
  k_posp   <<<NN/256,256,0,stream>>>(ppin,pos,sigg,n2g,Rm,Tm,posp,target);

  // prep
  k_wmg   <<<1,256,0,stream>>>(W_msg,w_gate,wmg);
  k_prep  <<<NN/4,256,0,stream>>>(x,wmg,xb,cf);
  k_wt    <<<(HD*HD)/256,256,0,stream>>>(W_node,wt_node);
  k_wt    <<<(HD*HD)/256,256,0,stream>>>(W_msg ,wt_msg);
  k_wt    <<<(HD*HD)/256,256,0,stream>>>(Wd1   ,wt_d1);
  k_cvtw  <<<(HD*HD)/256,256,0,stream>>>(Wd2,wd2b,HD*HD);
  k_wpe   <<<(HD*HD)/256,256,0,stream>>>(Wp1,wpeb);
  k_cvtw  <<<(HD*NL+255)/256,256,0,stream>>>(Wp2,wp2b,HD*NL);

  // CSR build
  k_count <<<NE/256,256,0,stream>>>(ei,cnt_e);
  k_scan_a<<<NN/256,256,0,stream>>>(cnt_e,start,bsum);
  k_scan_b<<<1,256,0,stream>>>(bsum);
  k_scan_c<<<NN/256,256,0,stream>>>(start,bsum,cursor);
  k_scatter<<<NE/256,256,0,stream>>>(ei,cursor,elist);

  // GNN
  k_gather<<<NN,256,0,stream>>>(xb,start,elist,xsb);
  gemmA<1><<<NN/64,256,0,stream>>>(xb ,xsb,wt_node,wt_msg,nullptr,xlb);  // xl
  gemmA<0><<<NN/64,256,0,stream>>>(xlb,nullptr,wt_d1,nullptr,bd1,h1b);  // h1

  // graph rep + head (ce)
  k_sg    <<<NG,256,0,stream>>>(h1b,gstart,sg);
  k_head  <<<NG,256,0,stream>>>(sg,gstart,bd2,wd2b,wpeb,bp1,wp2b,bp2,nl,accum);

  // position branch + denoise loss
  k_eloss <<<NN/256,256,0,stream>>>(start,elist,posp,cf,target,sigg,n2g,accum);

  k_final <<<1,1,0,stream>>>(accum,out);
}

// Round 3
// 418.113 us; speedup vs baseline: 3.0400x; 1.4908x over previous
//
#include <hip/hip_runtime.h>
#include <math.h>

#define NN 65536   // nodes
#define NE 524288  // edges
#define NG 2048    // graphs
#define HD 256     // hidden
#define NL 50      // noise levels

typedef unsigned short u16;
typedef __attribute__((ext_vector_type(8))) short short8;
typedef __attribute__((ext_vector_type(4))) float f32x4;
typedef __attribute__((ext_vector_type(4))) unsigned short us4;

__device__ __forceinline__ float bf2f(u16 h){
  union{unsigned int u; float f;} v; v.u = ((unsigned int)h)<<16; return v.f;
}
__device__ __forceinline__ u16 f2bf(float f){
  union{float f; unsigned int u;} v; v.f=f;
  return (u16)((v.u + 0x7FFFu + ((v.u>>16)&1u))>>16);
}
__device__ __forceinline__ float silu_f(float v){ return v/(1.0f+__expf(-v)); }

// ---------------- graph boundaries (n2g is sorted) ----------------
__global__ void k_gb(const int* __restrict__ n2g, int* __restrict__ gstart){
  int i = blockIdx.x*256 + threadIdx.x;
  if(i>NN) return;
  int cur  = (i<NN)? n2g[i] : NG;
  int prev = (i==0)? -1 : n2g[i-1];
  for(int g=prev+1; g<=cur; ++g) gstart[g]=i;
}

__global__ void k_sigg(const int* __restrict__ nl, float* __restrict__ sigg){
  int g = blockIdx.x*256+threadIdx.x; if(g>=NG) return;
  const double L0 =  2.3025850929940456840;  // ln 10
  const double L1 = -4.6051701859880913680;  // ln 0.01
  sigg[g] = (float)exp(L0 + (double)nl[g]*(L1-L0)/49.0);
}

// ---------------- Kabsch path ----------------

__global__ void k_perturb(const float* __restrict__ pos, const float* __restrict__ noise,
                          const int* __restrict__ n2g, const float* __restrict__ sigg,
                          float* __restrict__ ppin,
                          float* __restrict__ sum_pos, float* __restrict__ sum_pp){
  int i = blockIdx.x*256 + threadIdx.x;
  if(i>=NN) return;
  int g = n2g[i];
  float sg = sigg[g];
  float px=pos[i*3+0], py=pos[i*3+1], pz=pos[i*3+2];
  float qx=px+noise[i*3+0]*sg, qy=py+noise[i*3+1]*sg, qz=pz+noise[i*3+2]*sg;
  ppin[i*3+0]=qx; ppin[i*3+1]=qy; ppin[i*3+2]=qz;
  atomicAdd(&sum_pos[g*3+0],px); atomicAdd(&sum_pos[g*3+1],py); atomicAdd(&sum_pos[g*3+2],pz);
  atomicAdd(&sum_pp [g*3+0],qx); atomicAdd(&sum_pp [g*3+1],qy); atomicAdd(&sum_pp [g*3+2],qz);
}

__global__ void k_center(const float* __restrict__ sum_pos, const float* __restrict__ sum_pp,
                         const int* __restrict__ gstart,
                         float* __restrict__ center, float* __restrict__ pcenter){
  int g = blockIdx.x*256+threadIdx.x; if(g>=NG) return;
  float c = fmaxf((float)(gstart[g+1]-gstart[g]),1.0f);
  #pragma unroll
  for(int d=0;d<3;d++){ center[g*3+d]=sum_pos[g*3+d]/c; pcenter[g*3+d]=sum_pp[g*3+d]/c; }
}

__global__ void k_H(const float* __restrict__ pos, const float* __restrict__ ppin,
                    const int* __restrict__ n2g, const float* __restrict__ center,
                    const float* __restrict__ pcenter, float* __restrict__ Hm){
  int i = blockIdx.x*256+threadIdx.x; if(i>=NN) return;
  int g=n2g[i];
  float a0=ppin[i*3+0]-pcenter[g*3+0];
  float a1=ppin[i*3+1]-pcenter[g*3+1];
  float a2=ppin[i*3+2]-pcenter[g*3+2];
  float b0=pos[i*3+0]-center[g*3+0];
  float b1=pos[i*3+1]-center[g*3+1];
  float b2=pos[i*3+2]-center[g*3+2];
  atomicAdd(&Hm[g*9+0],a0*b0); atomicAdd(&Hm[g*9+1],a0*b1); atomicAdd(&Hm[g*9+2],a0*b2);
  atomicAdd(&Hm[g*9+3],a1*b0); atomicAdd(&Hm[g*9+4],a1*b1); atomicAdd(&Hm[g*9+5],a1*b2);
  atomicAdd(&Hm[g*9+6],a2*b0); atomicAdd(&Hm[g*9+7],a2*b1); atomicAdd(&Hm[g*9+8],a2*b2);
}

__global__ void k_polar(const float* __restrict__ Hm, const float* __restrict__ center,
                        const float* __restrict__ pcenter,
                        float* __restrict__ R, float* __restrict__ T){
  int g = blockIdx.x*256+threadIdx.x; if(g>=NG) return;
  float X[3][3];
  #pragma unroll
  for(int r=0;r<3;r++)
    #pragma unroll
    for(int c=0;c<3;c++) X[r][c]=Hm[g*9 + c*3 + r];   // X = H^T
  float nf=0.f;
  #pragma unroll
  for(int r=0;r<3;r++) for(int c=0;c<3;c++) nf += X[r][c]*X[r][c];
  nf = sqrtf(nf);
  if(nf < 1e-20f){
    #pragma unroll
    for(int r=0;r<3;r++) for(int c=0;c<3;c++) X[r][c]=(r==c)?1.f:0.f;
  } else {
    float s0=1.f/nf;
    #pragma unroll
    for(int r=0;r<3;r++) for(int c=0;c<3;c++) X[r][c]*=s0;
    for(int it=0; it<30; ++it){
      float a=X[0][0],b=X[0][1],c=X[0][2];
      float d=X[1][0],e=X[1][1],f=X[1][2];
      float gg=X[2][0],h=X[2][1],ii=X[2][2];
      float A_= e*ii-f*h, B_=-(d*ii-f*gg), C_= d*h-e*gg;
      float D_=-(b*ii-c*h), E_= a*ii-c*gg, F_=-(a*h-b*gg);
      float G_= b*f-c*e,  H_=-(a*f-c*d),  I_= a*e-b*d;
      float det = a*A_ + b*B_ + c*C_;
      if(!(fabsf(det) > 1e-25f)){
        if(it==0){
          for(int r=0;r<3;r++) for(int cc=0;cc<3;cc++) X[r][cc]=(r==cc)?1.f:0.f;
        }
        break;
      }
      float si = 0.5f/det;
      float Y00=0.5f*a + si*A_, Y01=0.5f*b + si*B_, Y02=0.5f*c + si*C_;
      float Y10=0.5f*d + si*D_, Y11=0.5f*e + si*E_, Y12=0.5f*f + si*F_;
      float Y20=0.5f*gg+ si*G_, Y21=0.5f*h + si*H_, Y22=0.5f*ii+ si*I_;
      X[0][0]=Y00; X[0][1]=Y01; X[0][2]=Y02;
      X[1][0]=Y10; X[1][1]=Y11; X[1][2]=Y12;
      X[2][0]=Y20; X[2][1]=Y21; X[2][2]=Y22;
    }
  }
  float pcx=pcenter[g*3+0], pcy=pcenter[g*3+1], pcz=pcenter[g*3+2];
  #pragma unroll
  for(int r=0;r<3;r++){
    T[g*3+r] = center[g*3+r] - (X[r][0]*pcx + X[r][1]*pcy + X[r][2]*pcz);
    #pragma unroll
    for(int c=0;c<3;c++) R[g*9+r*3+c]=X[r][c];
  }
}

__global__ void k_posp(const float* __restrict__ ppin, const float* __restrict__ pos,
                       const float* __restrict__ sigg, const int* __restrict__ n2g,
                       const float* __restrict__ R, const float* __restrict__ T,
                       float* __restrict__ posp, float* __restrict__ target){
  int i = blockIdx.x*256+threadIdx.x; if(i>=NN) return;
  int g=n2g[i];
  float qx=ppin[i*3+0], qy=ppin[i*3+1], qz=ppin[i*3+2];
  float px,py,pz;
  px = R[g*9+0]*qx + R[g*9+1]*qy + R[g*9+2]*qz + T[g*3+0];
  py = R[g*9+3]*qx + R[g*9+4]*qy + R[g*9+5]*qz + T[g*3+1];
  pz = R[g*9+6]*qx + R[g*9+7]*qy + R[g*9+8]*qz + T[g*3+2];
  posp[i*3+0]=px; posp[i*3+1]=py; posp[i*3+2]=pz;
  float is = 1.0f/sigg[g];
  target[i*3+0]=(pos[i*3+0]-px)*is;
  target[i*3+1]=(pos[i*3+1]-py)*is;
  target[i*3+2]=(pos[i*3+2]-pz)*is;
}

// ---------------- prep ----------------

__global__ void k_wmg(const float* __restrict__ Wmsg, const float* __restrict__ wgate,
                      float* __restrict__ wmg){
  int k = threadIdx.x;
  float s=0.f;
  for(int j=0;j<256;j++) s += Wmsg[k*256+j]*wgate[j];
  wmg[k]=s;
}

__global__ void k_prep(const float* __restrict__ x, const float* __restrict__ wmg,
                       u16* __restrict__ xb, float* __restrict__ cf){
  int wave = threadIdx.x>>6, lane = threadIdx.x&63;
  int i = blockIdx.x*4 + wave;
  float4 a = ((const float4*)(x + (size_t)i*256))[lane];
  float4 b = ((const float4*)wmg)[lane];
  float s = a.x*b.x + a.y*b.y + a.z*b.z + a.w*b.w;
  us4 o; o.x=f2bf(a.x); o.y=f2bf(a.y); o.z=f2bf(a.z); o.w=f2bf(a.w);
  *(us4*)(xb + (size_t)i*256 + lane*4) = o;
  #pragma unroll
  for(int of=32;of;of>>=1) s += __shfl_down(s,of);
  if(lane==0) cf[i]=silu_f(s);
}

// Wt[n][k] = bf16(W[k][n])
__global__ void k_wt(const float* __restrict__ W, u16* __restrict__ Wt){
  int idx = blockIdx.x*256+threadIdx.x;   // 65536
  int k = idx>>8, n = idx&255;
  Wt[n*256+k] = f2bf(W[k*256+n]);
}

__global__ void k_cvtw(const float* __restrict__ W, u16* __restrict__ Wb, int n){
  int idx = blockIdx.x*256+threadIdx.x; if(idx>=n) return;
  Wb[idx] = f2bf(W[idx]);
}

__global__ void k_wpe(const float* __restrict__ Wp1, u16* __restrict__ Wpe){
  int idx = blockIdx.x*256+threadIdx.x;   // 65536
  Wpe[idx] = f2bf(Wp1[idx] + Wp1[idx + 65536]);
}

// ---------------- CSR build ----------------

__global__ void k_count(const int* __restrict__ ei, int* __restrict__ cnt_e){
  int e = blockIdx.x*256+threadIdx.x; if(e>=NE) return;
  atomicAdd(&cnt_e[ei[NE+e]],1);
}

__global__ void k_scan_a(const int* __restrict__ cnt_e, int* __restrict__ start,
                         int* __restrict__ bsum){
  __shared__ int sh[256];
  int b=blockIdx.x, t=threadIdx.x, i=b*256+t;
  int v = cnt_e[i]; sh[t]=v; __syncthreads();
  #pragma unroll
  for(int o=1;o<256;o<<=1){
    int u = (t>=o)? sh[t-o]:0; __syncthreads(); sh[t]+=u; __syncthreads();
  }
  start[i] = sh[t]-v;
  if(t==255) bsum[b]=sh[255];
}

__global__ void k_scan_b(int* __restrict__ bsum){
  __shared__ int sh[256];
  int t=threadIdx.x; int v=bsum[t]; sh[t]=v; __syncthreads();
  #pragma unroll
  for(int o=1;o<256;o<<=1){
    int u=(t>=o)?sh[t-o]:0; __syncthreads(); sh[t]+=u; __syncthreads();
  }
  bsum[t]=sh[t]-v;
}

__global__ void k_scan_c(int* __restrict__ start, const int* __restrict__ bsum,
                         int* __restrict__ cursor){
  int b=blockIdx.x, i=b*256+threadIdx.x;
  int v = start[i]+bsum[b];
  start[i]=v; cursor[i]=v;
  if(i==0) start[NN]=NE;
}

__global__ void k_scatter(const int* __restrict__ ei, int* __restrict__ cursor,
                          int* __restrict__ elist){
  int e = blockIdx.x*256+threadIdx.x; if(e>=NE) return;
  int c = ei[NE+e];
  int p = atomicAdd(&cursor[c],1);
  elist[p] = ei[e];
}

// ---------------- neighbor gather: xs[c] = sum_{r in N(c)} xb[r] ----------------
// one wave per node, us4 per lane (64*4 = 256 cols)
__global__ void k_gather(const u16* __restrict__ xb, const int* __restrict__ start,
                         const int* __restrict__ elist, u16* __restrict__ xsb){
  int c = blockIdx.x, lane = threadIdx.x;
  int s0=start[c], s1=start[c+1];
  float a0=0.f,a1=0.f,a2=0.f,a3=0.f;
  int e=s0;
  for(; e+1<s1; e+=2){
    int r0=elist[e], r1=elist[e+1];
    us4 v0 = *(const us4*)(xb + (size_t)r0*256 + lane*4);
    us4 v1 = *(const us4*)(xb + (size_t)r1*256 + lane*4);
    a0 += bf2f(v0.x)+bf2f(v1.x); a1 += bf2f(v0.y)+bf2f(v1.y);
    a2 += bf2f(v0.z)+bf2f(v1.z); a3 += bf2f(v0.w)+bf2f(v1.w);
  }
  if(e<s1){
    us4 v0 = *(const us4*)(xb + (size_t)elist[e]*256 + lane*4);
    a0+=bf2f(v0.x); a1+=bf2f(v0.y); a2+=bf2f(v0.z); a3+=bf2f(v0.w);
  }
  us4 o; o.x=f2bf(a0); o.y=f2bf(a1); o.z=f2bf(a2); o.w=f2bf(a3);
  *(us4*)(xsb + (size_t)c*256 + lane*4) = o;
}

// ---------------- LDS-staged MFMA GEMM ----------------
// Block: 256 thr (4 waves). Output tile: 256 rows x 128 cols (half of N).
// Wave w: rows [chunk*256 + w*64, +64), cols [half*128, +128) -> acc[4 m-tiles][8 n-tiles].
// B half-tile (128 rows x 256 k, bf16 = 64KB) staged in LDS with XOR swizzle
// (byte ^= (row&7)<<4) so the 16-lane ds_read_b128 column reads are conflict-free.
// DUAL: phase0 A1@B1half, restage B2half, phase1 A2@B2half, same accumulators.
template<int DUAL>
__global__ __launch_bounds__(256,2) void gemmB(const u16* __restrict__ A1, const u16* __restrict__ A2,
                       const u16* __restrict__ B1, const u16* __restrict__ B2,
                       const float* __restrict__ bias, u16* __restrict__ outb){
  __shared__ u16 Bs[128*256];  // 64 KB
  int t = threadIdx.x;
  int wave = t>>6, lane = t&63;
  int half  = blockIdx.x & 1;
  int chunk = blockIdx.x >> 1;
  int m0 = chunk*256 + wave*64;
  int lr = lane&15, lk = (lane>>4)*8;

  // stage B1 half
  {
    const u16* src = B1 + (size_t)half*128*256;
    #pragma unroll
    for(int it=0; it<16; ++it){
      int idx = (it*256 + t)*8;               // u16 index
      short8 v = *(const short8*)(src + idx);
      unsigned baddr = (unsigned)idx*2;
      baddr ^= ((baddr>>9)&7u)<<4;
      *(short8*)((char*)Bs + baddr) = v;
    }
  }
  __syncthreads();

  f32x4 acc[4][8];
  #pragma unroll
  for(int mi=0;mi<4;mi++)
    #pragma unroll
    for(int nt=0;nt<8;nt++) acc[mi][nt]=(f32x4){0.f,0.f,0.f,0.f};

  // phase 0: A1 x B1
  #pragma unroll
  for(int k0=0;k0<256;k0+=32){
    short8 a[4], b[8];
    #pragma unroll
    for(int mi=0;mi<4;mi++)
      a[mi] = *(const short8*)(A1 + (size_t)(m0+mi*16+lr)*256 + k0 + lk);
    #pragma unroll
    for(int nt=0;nt<8;nt++){
      unsigned row = nt*16 + lr;
      unsigned baddr = row*512 + (k0+lk)*2;
      baddr ^= ((row&7u)<<4);
      b[nt] = *(const short8*)((char*)Bs + baddr);
    }
    #pragma unroll
    for(int mi=0;mi<4;mi++)
      #pragma unroll
      for(int nt=0;nt<8;nt++)
        acc[mi][nt] = __builtin_amdgcn_mfma_f32_16x16x32_bf16(a[mi],b[nt],acc[mi][nt],0,0,0);
  }

  if(DUAL){
    __syncthreads();
    {
      const u16* src = B2 + (size_t)half*128*256;
      #pragma unroll
      for(int it=0; it<16; ++it){
        int idx = (it*256 + t)*8;
        short8 v = *(const short8*)(src + idx);
        unsigned baddr = (unsigned)idx*2;
        baddr ^= ((baddr>>9)&7u)<<4;
        *(short8*)((char*)Bs + baddr) = v;
      }
    }
    __syncthreads();
    #pragma unroll
    for(int k0=0;k0<256;k0+=32){
      short8 a[4], b[8];
      #pragma unroll
      for(int mi=0;mi<4;mi++)
        a[mi] = *(const short8*)(A2 + (size_t)(m0+mi*16+lr)*256 + k0 + lk);
      #pragma unroll
      for(int nt=0;nt<8;nt++){
        unsigned row = nt*16 + lr;
        unsigned baddr = row*512 + (k0+lk)*2;
        baddr ^= ((row&7u)<<4);
        b[nt] = *(const short8*)((char*)Bs + baddr);
      }
      #pragma unroll
      for(int mi=0;mi<4;mi++)
        #pragma unroll
        for(int nt=0;nt<8;nt++)
          acc[mi][nt] = __builtin_amdgcn_mfma_f32_16x16x32_bf16(a[mi],b[nt],acc[mi][nt],0,0,0);
    }
  }

  // epilogue
  int rloc = (lane>>4)*4;
  #pragma unroll
  for(int mi=0;mi<4;mi++){
    #pragma unroll
    for(int j=0;j<4;j++){
      size_t r = m0 + mi*16 + rloc + j;
      #pragma unroll
      for(int nt=0;nt<8;nt++){
        int c = half*128 + nt*16 + lr;
        float v = acc[mi][nt][j];
        if(!DUAL) v += bias[c];
        outb[r*256 + c] = f2bf(silu_f(v));
      }
    }
  }
}

// ---------------- per-graph seg-sum of h1 (one wave per graph) ----------------

__global__ void k_sg(const u16* __restrict__ h1b, const int* __restrict__ gstart,
                     float* __restrict__ sg){
  int g = blockIdx.x, lane = threadIdx.x;
  int s0=gstart[g], s1=gstart[g+1];
  float a0=0.f,a1=0.f,a2=0.f,a3=0.f;
  for(int i=s0;i<s1;i++){
    us4 v = *(const us4*)(h1b + (size_t)i*256 + lane*4);
    a0+=bf2f(v.x); a1+=bf2f(v.y); a2+=bf2f(v.z); a3+=bf2f(v.w);
  }
  float4 o; o.x=a0; o.y=a1; o.z=a2; o.w=a3;
  *(float4*)(sg + (size_t)g*256 + lane*4) = o;
}

// ---------------- fused head ----------------

__global__ __launch_bounds__(256) void k_head(const float* __restrict__ sg, const int* __restrict__ gstart,
                       const float* __restrict__ bd2, const u16* __restrict__ wd2b,
                       const u16* __restrict__ wpeb, const float* __restrict__ bp1,
                       const u16* __restrict__ wp2b, const float* __restrict__ bp2,
                       const int* __restrict__ nl, float* __restrict__ accum){
  __shared__ float sh[256];
  __shared__ float xg[256];
  __shared__ float hh[256];
  int g = blockIdx.x, t = threadIdx.x;
  sh[t] = sg[(size_t)g*256+t];
  float cntg = (float)(gstart[g+1]-gstart[g]);
  __syncthreads();
  {
    float s = cntg*bd2[t];
    for(int k=0;k<256;k++) s += sh[k]*bf2f(wd2b[k*256+t]);
    xg[t] = s;
  }
  __syncthreads();
  {
    float s = bp1[t];
    for(int k=0;k<256;k++) s += xg[k]*bf2f(wpeb[k*256+t]);
    hh[t] = silu_f(s);
  }
  __syncthreads();
  if(t<64){
    float logit = -1e30f;
    if(t<NL){
      float s = bp2[t];
      for(int k=0;k<256;k++) s += hh[k]*bf2f(wp2b[k*NL+t]);
      logit = s;
    }
    float mx = logit;
    #pragma unroll
    for(int o=32;o;o>>=1) mx = fmaxf(mx, __shfl_xor(mx,o));
    float ex = (t<NL)? __expf(logit-mx) : 0.f;
    float se = ex;
    #pragma unroll
    for(int o=32;o;o>>=1) se += __shfl_xor(se,o);
    float lse = logf(se)+mx;
    float lsel = __shfl(logit, nl[g]);
    if(t==0) atomicAdd(&accum[1], lse - lsel);
  }
}

// ---------------- fused edge-delta + denoise loss ----------------

__global__ void k_eloss(const int* __restrict__ start, const int* __restrict__ elist,
                        const float* __restrict__ posp, const float* __restrict__ cf,
                        const float* __restrict__ target, const float* __restrict__ sigg,
                        const int* __restrict__ n2g, float* __restrict__ accum){
  int i = blockIdx.x*256+threadIdx.x;
  float s=0.f;
  if(i<NN){
    int s0=start[i], s1=start[i+1];
    float px=posp[i*3+0], py=posp[i*3+1], pz=posp[i*3+2];
    float dx=0.f, dy=0.f, dz=0.f;
    for(int e=s0;e<s1;e++){
      int r=elist[e];
      float c=cf[r];
      dx += (posp[r*3+0]-px)*c;
      dy += (posp[r*3+1]-py)*c;
      dz += (posp[r*3+2]-pz)*c;
    }
    float is = 1.f/sigg[n2g[i]];
    float d0 = dx*is - target[i*3+0];
    float d1 = dy*is - target[i*3+1];
    float d2 = dz*is - target[i*3+2];
    s = d0*d0+d1*d1+d2*d2;
  }
  #pragma unroll
  for(int o=32;o;o>>=1) s += __shfl_down(s,o);
  if((threadIdx.x&63)==0) atomicAdd(&accum[0], s);
}

__global__ void k_final(const float* __restrict__ accum, float* __restrict__ out){
  out[0] = accum[0]/(float)NG;
  out[1] = accum[1]/(float)NG;
}

// ---------------- launcher ----------------

extern "C" void kernel_launch(void* const* d_in, const int* in_sizes, int n_in,
                              void* d_out, int out_size, void* d_ws, size_t ws_size,
                              hipStream_t stream){
  (void)in_sizes; (void)n_in; (void)out_size; (void)ws_size;
  const float* x      = (const float*)d_in[0];
  const float* pos    = (const float*)d_in[1];
  const float* noise  = (const float*)d_in[2];
  const int*   n2g    = (const int*)d_in[3];
  const int*   ei     = (const int*)d_in[4];
  const int*   nl     = (const int*)d_in[5];
  const float* W_node = (const float*)d_in[6];
  const float* W_msg  = (const float*)d_in[7];
  const float* w_gate = (const float*)d_in[8];
  const float* Wd1    = (const float*)d_in[9];
  const float* bd1    = (const float*)d_in[10];
  const float* Wd2    = (const float*)d_in[11];
  const float* bd2    = (const float*)d_in[12];
  const float* Wp1    = (const float*)d_in[17];
  const float* bp1    = (const float*)d_in[18];
  const float* Wp2    = (const float*)d_in[19];
  const float* bp2    = (const float*)d_in[20];
  float* out = (float*)d_out;

  char* w = (char*)d_ws;
  size_t off = 0;
  auto alloc = [&](size_t bytes)->void*{
    void* p = w + off;
    off += (bytes + 255) & ~(size_t)255;
    return p;
  };

  // --- zeroed region ---
  size_t zstart = off;
  int*   cnt_e   = (int*)alloc((size_t)NN*4);
  float* sum_pos = (float*)alloc((size_t)NG*3*4);
  float* sum_pp  = (float*)alloc((size_t)NG*3*4);
  float* Hm      = (float*)alloc((size_t)NG*9*4);
  float* accum   = (float*)alloc(2*4);
  size_t zend = off;

  // --- other buffers ---
  u16*  xb   = (u16*)alloc((size_t)NN*HD*2);
  u16*  xsb  = (u16*)alloc((size_t)NN*HD*2);
  u16*  xlb  = (u16*)alloc((size_t)NN*HD*2);
  u16*  h1b  = (u16*)alloc((size_t)NN*HD*2);
  float* sg     = (float*)alloc((size_t)NG*HD*4);
  float* sigg   = (float*)alloc((size_t)NG*4);
  float* ppin   = (float*)alloc((size_t)NN*3*4);
  float* posp   = (float*)alloc((size_t)NN*3*4);
  float* target = (float*)alloc((size_t)NN*3*4);
  float* cf     = (float*)alloc((size_t)NN*4);
  float* center = (float*)alloc((size_t)NG*3*4);
  float* pcenter= (float*)alloc((size_t)NG*3*4);
  float* Rm     = (float*)alloc((size_t)NG*9*4);
  float* Tm     = (float*)alloc((size_t)NG*3*4);
  int*  gstart  = (int*)alloc((size_t)(NG+1)*4);
  int*  start   = (int*)alloc((size_t)(NN+1)*4);
  int*  cursor  = (int*)alloc((size_t)NN*4);
  int*  bsum    = (int*)alloc((size_t)256*4);
  int*  elist   = (int*)alloc((size_t)NE*4);
  u16*  wt_node = (u16*)alloc((size_t)HD*HD*2);
  u16*  wt_msg  = (u16*)alloc((size_t)HD*HD*2);
  u16*  wt_d1   = (u16*)alloc((size_t)HD*HD*2);
  u16*  wd2b    = (u16*)alloc((size_t)HD*HD*2);
  u16*  wpeb    = (u16*)alloc((size_t)HD*HD*2);
  u16*  wp2b    = (u16*)alloc((size_t)HD*NL*2);
  float* wmg    = (float*)alloc((size_t)HD*4);

  hipMemsetAsync(w+zstart, 0, zend-zstart, stream);

  // graph structure
  k_gb    <<<(NN+256)/256,256,0,stream>>>(n2g,gstart);
  k_sigg  <<<NG/256,256,0,stream>>>(nl,sigg);

  // Kabsch path
  k_perturb<<<NN/256,256,0,stream>>>(pos,noise,n2g,sigg,ppin,sum_pos,sum_pp);
  k_center <<<NG/256,256,0,stream>>>(sum_pos,sum_pp,gstart,center,pcenter);
  k_H      <<<NN/256,256,0,stream>>>(pos,ppin,n2g,center,pcenter,Hm);
  k_polar  <<<NG/256,256,0,stream>>>(Hm,center,pcenter,Rm,Tm);
  k_posp   <<<NN/256,256,0,stream>>>(ppin,pos,sigg,n2g,Rm,Tm,posp,target);

  // prep
  k_wmg   <<<1,256,0,stream>>>(W_msg,w_gate,wmg);
  k_prep  <<<NN/4,256,0,stream>>>(x,wmg,xb,cf);
  k_wt    <<<(HD*HD)/256,256,0,stream>>>(W_node,wt_node);
  k_wt    <<<(HD*HD)/256,256,0,stream>>>(W_msg ,wt_msg);
  k_wt    <<<(HD*HD)/256,256,0,stream>>>(Wd1   ,wt_d1);
  k_cvtw  <<<(HD*HD)/256,256,0,stream>>>(Wd2,wd2b,HD*HD);
  k_wpe   <<<(HD*HD)/256,256,0,stream>>>(Wp1,wpeb);
  k_cvtw  <<<(HD*NL+255)/256,256,0,stream>>>(Wp2,wp2b,HD*NL);

  // CSR build
  k_count <<<NE/256,256,0,stream>>>(ei,cnt_e);
  k_scan_a<<<NN/256,256,0,stream>>>(cnt_e,start,bsum);
  k_scan_b<<<1,256,0,stream>>>(bsum);
  k_scan_c<<<NN/256,256,0,stream>>>(start,bsum,cursor);
  k_scatter<<<NE/256,256,0,stream>>>(ei,cursor,elist);

  // GNN
  k_gather<<<NN,64,0,stream>>>(xb,start,elist,xsb);
  gemmB<1><<<512,256,0,stream>>>(xb ,xsb,wt_node,wt_msg,nullptr,xlb);  // xl
  gemmB<0><<<512,256,0,stream>>>(xlb,nullptr,wt_d1,nullptr,bd1,h1b);   // h1

  // graph rep + head (ce)
  k_sg    <<<NG,64,0,stream>>>(h1b,gstart,sg);
  k_head  <<<NG,256,0,stream>>>(sg,gstart,bd2,wd2b,wpeb,bp1,wp2b,bp2,nl,accum);

  // position branch + denoise loss
  k_eloss <<<NN/256,256,0,stream>>>(start,elist,posp,cf,target,sigg,n2g,accum);

  k_final <<<1,1,0,stream>>>(accum,out);
}

// Round 4
// 408.749 us; speedup vs baseline: 3.1097x; 1.0229x over previous
//
#include <hip/hip_runtime.h>
#include <math.h>

#define NN 65536   // nodes
#define NE 524288  // edges
#define NG 2048    // graphs
#define HD 256     // hidden
#define NL 50      // noise levels

typedef unsigned short u16;
typedef __attribute__((ext_vector_type(8))) short short8;
typedef __attribute__((ext_vector_type(4))) float f32x4;
typedef __attribute__((ext_vector_type(4))) unsigned short us4;

__device__ __forceinline__ float bf2f(u16 h){
  union{unsigned int u; float f;} v; v.u = ((unsigned int)h)<<16; return v.f;
}
__device__ __forceinline__ u16 f2bf(float f){
  union{float f; unsigned int u;} v; v.f=f;
  return (u16)((v.u + 0x7FFFu + ((v.u>>16)&1u))>>16);
}
__device__ __forceinline__ float silu_f(float v){ return v/(1.0f+__expf(-v)); }

// ---------------- graph boundaries (n2g is sorted) ----------------
__global__ void k_gb(const int* __restrict__ n2g, int* __restrict__ gstart){
  int i = blockIdx.x*256 + threadIdx.x;
  if(i>NN) return;
  int cur  = (i<NN)? n2g[i] : NG;
  int prev = (i==0)? -1 : n2g[i-1];
  for(int g=prev+1; g<=cur; ++g) gstart[g]=i;
}

__global__ void k_sigg(const int* __restrict__ nl, float* __restrict__ sigg){
  int g = blockIdx.x*256+threadIdx.x; if(g>=NG) return;
  const double L0 =  2.3025850929940456840;  // ln 10
  const double L1 = -4.6051701859880913680;  // ln 0.01
  sigg[g] = (float)exp(L0 + (double)nl[g]*(L1-L0)/49.0);
}

__global__ void k_cnt(const int* __restrict__ gstart, float* __restrict__ cntf){
  int g = blockIdx.x*256+threadIdx.x; if(g>=NG) return;
  cntf[g] = (float)(gstart[g+1]-gstart[g]);
}

// ---------------- Kabsch path ----------------

__global__ void k_perturb(const float* __restrict__ pos, const float* __restrict__ noise,
                          const int* __restrict__ n2g, const float* __restrict__ sigg,
                          float* __restrict__ ppin,
                          float* __restrict__ sum_pos, float* __restrict__ sum_pp){
  int i = blockIdx.x*256 + threadIdx.x;
  if(i>=NN) return;
  int g = n2g[i];
  float sg = sigg[g];
  float px=pos[i*3+0], py=pos[i*3+1], pz=pos[i*3+2];
  float qx=px+noise[i*3+0]*sg, qy=py+noise[i*3+1]*sg, qz=pz+noise[i*3+2]*sg;
  ppin[i*3+0]=qx; ppin[i*3+1]=qy; ppin[i*3+2]=qz;
  atomicAdd(&sum_pos[g*3+0],px); atomicAdd(&sum_pos[g*3+1],py); atomicAdd(&sum_pos[g*3+2],pz);
  atomicAdd(&sum_pp [g*3+0],qx); atomicAdd(&sum_pp [g*3+1],qy); atomicAdd(&sum_pp [g*3+2],qz);
}

__global__ void k_center(const float* __restrict__ sum_pos, const float* __restrict__ sum_pp,
                         const int* __restrict__ gstart,
                         float* __restrict__ center, float* __restrict__ pcenter){
  int g = blockIdx.x*256+threadIdx.x; if(g>=NG) return;
  float c = fmaxf((float)(gstart[g+1]-gstart[g]),1.0f);
  #pragma unroll
  for(int d=0;d<3;d++){ center[g*3+d]=sum_pos[g*3+d]/c; pcenter[g*3+d]=sum_pp[g*3+d]/c; }
}

__global__ void k_H(const float* __restrict__ pos, const float* __restrict__ ppin,
                    const int* __restrict__ n2g, const float* __restrict__ center,
                    const float* __restrict__ pcenter, float* __restrict__ Hm){
  int i = blockIdx.x*256+threadIdx.x; if(i>=NN) return;
  int g=n2g[i];
  float a0=ppin[i*3+0]-pcenter[g*3+0];
  float a1=ppin[i*3+1]-pcenter[g*3+1];
  float a2=ppin[i*3+2]-pcenter[g*3+2];
  float b0=pos[i*3+0]-center[g*3+0];
  float b1=pos[i*3+1]-center[g*3+1];
  float b2=pos[i*3+2]-center[g*3+2];
  atomicAdd(&Hm[g*9+0],a0*b0); atomicAdd(&Hm[g*9+1],a0*b1); atomicAdd(&Hm[g*9+2],a0*b2);
  atomicAdd(&Hm[g*9+3],a1*b0); atomicAdd(&Hm[g*9+4],a1*b1); atomicAdd(&Hm[g*9+5],a1*b2);
  atomicAdd(&Hm[g*9+6],a2*b0); atomicAdd(&Hm[g*9+7],a2*b1); atomicAdd(&Hm[g*9+8],a2*b2);
}

__global__ void k_polar(const float* __restrict__ Hm, const float* __restrict__ center,
                        const float* __restrict__ pcenter,
                        float* __restrict__ R, float* __restrict__ T){
  int g = blockIdx.x*256+threadIdx.x; if(g>=NG) return;
  float X[3][3];
  #pragma unroll
  for(int r=0;r<3;r++)
    #pragma unroll
    for(int c=0;c<3;c++) X[r][c]=Hm[g*9 + c*3 + r];   // X = H^T
  float nf=0.f;
  #pragma unroll
  for(int r=0;r<3;r++) for(int c=0;c<3;c++) nf += X[r][c]*X[r][c];
  nf = sqrtf(nf);
  if(nf < 1e-20f){
    #pragma unroll
    for(int r=0;r<3;r++) for(int c=0;c<3;c++) X[r][c]=(r==c)?1.f:0.f;
  } else {
    float s0=1.f/nf;
    #pragma unroll
    for(int r=0;r<3;r++) for(int c=0;c<3;c++) X[r][c]*=s0;
    for(int it=0; it<30; ++it){
      float a=X[0][0],b=X[0][1],c=X[0][2];
      float d=X[1][0],e=X[1][1],f=X[1][2];
      float gg=X[2][0],h=X[2][1],ii=X[2][2];
      float A_= e*ii-f*h, B_=-(d*ii-f*gg), C_= d*h-e*gg;
      float D_=-(b*ii-c*h), E_= a*ii-c*gg, F_=-(a*h-b*gg);
      float G_= b*f-c*e,  H_=-(a*f-c*d),  I_= a*e-b*d;
      float det = a*A_ + b*B_ + c*C_;
      if(!(fabsf(det) > 1e-25f)){
        if(it==0){
          for(int r=0;r<3;r++) for(int cc=0;cc<3;cc++) X[r][cc]=(r==cc)?1.f:0.f;
        }
        break;
      }
      float si = 0.5f/det;
      float Y00=0.5f*a + si*A_, Y01=0.5f*b + si*B_, Y02=0.5f*c + si*C_;
      float Y10=0.5f*d + si*D_, Y11=0.5f*e + si*E_, Y12=0.5f*f + si*F_;
      float Y20=0.5f*gg+ si*G_, Y21=0.5f*h + si*H_, Y22=0.5f*ii+ si*I_;
      X[0][0]=Y00; X[0][1]=Y01; X[0][2]=Y02;
      X[1][0]=Y10; X[1][1]=Y11; X[1][2]=Y12;
      X[2][0]=Y20; X[2][1]=Y21; X[2][2]=Y22;
    }
  }
  float pcx=pcenter[g*3+0], pcy=pcenter[g*3+1], pcz=pcenter[g*3+2];
  #pragma unroll
  for(int r=0;r<3;r++){
    T[g*3+r] = center[g*3+r] - (X[r][0]*pcx + X[r][1]*pcy + X[r][2]*pcz);
    #pragma unroll
    for(int c=0;c<3;c++) R[g*9+r*3+c]=X[r][c];
  }
}

__global__ void k_posp(const float* __restrict__ ppin, const float* __restrict__ pos,
                       const float* __restrict__ sigg, const int* __restrict__ n2g,
                       const float* __restrict__ R, const float* __restrict__ T,
                       float* __restrict__ posp, float* __restrict__ target){
  int i = blockIdx.x*256+threadIdx.x; if(i>=NN) return;
  int g=n2g[i];
  float qx=ppin[i*3+0], qy=ppin[i*3+1], qz=ppin[i*3+2];
  float px,py,pz;
  px = R[g*9+0]*qx + R[g*9+1]*qy + R[g*9+2]*qz + T[g*3+0];
  py = R[g*9+3]*qx + R[g*9+4]*qy + R[g*9+5]*qz + T[g*3+1];
  pz = R[g*9+6]*qx + R[g*9+7]*qy + R[g*9+8]*qz + T[g*3+2];
  posp[i*3+0]=px; posp[i*3+1]=py; posp[i*3+2]=pz;
  float is = 1.0f/sigg[g];
  target[i*3+0]=(pos[i*3+0]-px)*is;
  target[i*3+1]=(pos[i*3+1]-py)*is;
  target[i*3+2]=(pos[i*3+2]-pz)*is;
}

// ---------------- prep ----------------

__global__ void k_wmg(const float* __restrict__ Wmsg, const float* __restrict__ wgate,
                      float* __restrict__ wmg){
  int k = threadIdx.x;
  float s=0.f;
  for(int j=0;j<256;j++) s += Wmsg[k*256+j]*wgate[j];
  wmg[k]=s;
}

__global__ void k_prep(const float* __restrict__ x, const float* __restrict__ wmg,
                       u16* __restrict__ xb, float* __restrict__ cf){
  int wave = threadIdx.x>>6, lane = threadIdx.x&63;
  int i = blockIdx.x*4 + wave;
  float4 a = ((const float4*)(x + (size_t)i*256))[lane];
  float4 b = ((const float4*)wmg)[lane];
  float s = a.x*b.x + a.y*b.y + a.z*b.z + a.w*b.w;
  us4 o; o.x=f2bf(a.x); o.y=f2bf(a.y); o.z=f2bf(a.z); o.w=f2bf(a.w);
  *(us4*)(xb + (size_t)i*256 + lane*4) = o;
  #pragma unroll
  for(int of=32;of;of>>=1) s += __shfl_down(s,of);
  if(lane==0) cf[i]=silu_f(s);
}

// Wt[n][k] = bf16(W[k][n])
__global__ void k_wt(const float* __restrict__ W, u16* __restrict__ Wt){
  int idx = blockIdx.x*256+threadIdx.x;   // 65536
  int k = idx>>8, n = idx&255;
  Wt[n*256+k] = f2bf(W[k*256+n]);
}

// wpet[n][k] = bf16(Wp1[k][n] + Wp1[k+256][n])
__global__ void k_wpe(const float* __restrict__ Wp1, u16* __restrict__ Wpe){
  int idx = blockIdx.x*256+threadIdx.x;   // 65536
  int k = idx>>8, n = idx&255;
  Wpe[n*256+k] = f2bf(Wp1[k*256+n] + Wp1[(k+256)*256+n]);
}

// wp2t[n][k] = bf16(Wp2[k][n]) for n<50, else 0.  (64 x 256)
__global__ void k_wp2(const float* __restrict__ Wp2, u16* __restrict__ Wt){
  int idx = blockIdx.x*256+threadIdx.x;   // 64*256
  int k = idx&255, n = idx>>8;
  Wt[n*256+k] = (n<NL)? f2bf(Wp2[k*NL+n]) : (u16)0;
}

// ---------------- CSR build ----------------

__global__ void k_count(const int* __restrict__ ei, int* __restrict__ cnt_e){
  int e = blockIdx.x*256+threadIdx.x; if(e>=NE) return;
  atomicAdd(&cnt_e[ei[NE+e]],1);
}

__global__ void k_scan_a(const int* __restrict__ cnt_e, int* __restrict__ start,
                         int* __restrict__ bsum){
  __shared__ int sh[256];
  int b=blockIdx.x, t=threadIdx.x, i=b*256+t;
  int v = cnt_e[i]; sh[t]=v; __syncthreads();
  #pragma unroll
  for(int o=1;o<256;o<<=1){
    int u = (t>=o)? sh[t-o]:0; __syncthreads(); sh[t]+=u; __syncthreads();
  }
  start[i] = sh[t]-v;
  if(t==255) bsum[b]=sh[255];
}

__global__ void k_scan_b(int* __restrict__ bsum){
  __shared__ int sh[256];
  int t=threadIdx.x; int v=bsum[t]; sh[t]=v; __syncthreads();
  #pragma unroll
  for(int o=1;o<256;o<<=1){
    int u=(t>=o)?sh[t-o]:0; __syncthreads(); sh[t]+=u; __syncthreads();
  }
  bsum[t]=sh[t]-v;
}

__global__ void k_scan_c(int* __restrict__ start, const int* __restrict__ bsum,
                         int* __restrict__ cursor){
  int b=blockIdx.x, i=b*256+threadIdx.x;
  int v = start[i]+bsum[b];
  start[i]=v; cursor[i]=v;
  if(i==0) start[NN]=NE;
}

__global__ void k_scatter(const int* __restrict__ ei, int* __restrict__ cursor,
                          int* __restrict__ elist){
  int e = blockIdx.x*256+threadIdx.x; if(e>=NE) return;
  int c = ei[NE+e];
  int p = atomicAdd(&cursor[c],1);
  elist[p] = ei[e];
}

// ---------------- neighbor gather ----------------
__global__ void k_gather(const u16* __restrict__ xb, const int* __restrict__ start,
                         const int* __restrict__ elist, u16* __restrict__ xsb){
  int c = blockIdx.x, lane = threadIdx.x;
  int s0=start[c], s1=start[c+1];
  float a0=0.f,a1=0.f,a2=0.f,a3=0.f;
  int e=s0;
  for(; e+1<s1; e+=2){
    int r0=elist[e], r1=elist[e+1];
    us4 v0 = *(const us4*)(xb + (size_t)r0*256 + lane*4);
    us4 v1 = *(const us4*)(xb + (size_t)r1*256 + lane*4);
    a0 += bf2f(v0.x)+bf2f(v1.x); a1 += bf2f(v0.y)+bf2f(v1.y);
    a2 += bf2f(v0.z)+bf2f(v1.z); a3 += bf2f(v0.w)+bf2f(v1.w);
  }
  if(e<s1){
    us4 v0 = *(const us4*)(xb + (size_t)elist[e]*256 + lane*4);
    a0+=bf2f(v0.x); a1+=bf2f(v0.y); a2+=bf2f(v0.z); a3+=bf2f(v0.w);
  }
  us4 o; o.x=f2bf(a0); o.y=f2bf(a1); o.z=f2bf(a2); o.w=f2bf(a3);
  *(us4*)(xsb + (size_t)c*256 + lane*4) = o;
}

// ---------------- LDS-staged MFMA GEMM (256-col output) ----------------
// MODE 0: dual  out = bf16(silu(A1@B1 + A2@B2))
// MODE 1: single out = bf16(silu(A1@B1 + bias[c]))
// MODE 2: single out = bf16(A1@B1 + extra[r]*bias[c])
template<int MODE>
__global__ __launch_bounds__(256,2) void gemmB(const u16* __restrict__ A1, const u16* __restrict__ A2,
                       const u16* __restrict__ B1, const u16* __restrict__ B2,
                       const float* __restrict__ bias, const float* __restrict__ extra,
                       u16* __restrict__ outb){
  __shared__ u16 Bs[128*256];  // 64 KB
  int t = threadIdx.x;
  int wave = t>>6, lane = t&63;
  int half  = blockIdx.x & 1;
  int chunk = blockIdx.x >> 1;
  int m0 = chunk*256 + wave*64;
  int lr = lane&15, lk = (lane>>4)*8;

  {
    const u16* src = B1 + (size_t)half*128*256;
    #pragma unroll
    for(int it=0; it<16; ++it){
      int idx = (it*256 + t)*8;
      short8 v = *(const short8*)(src + idx);
      unsigned baddr = (unsigned)idx*2;
      baddr ^= ((baddr>>9)&7u)<<4;
      *(short8*)((char*)Bs + baddr) = v;
    }
  }
  __syncthreads();

  f32x4 acc[4][8];
  #pragma unroll
  for(int mi=0;mi<4;mi++)
    #pragma unroll
    for(int nt=0;nt<8;nt++) acc[mi][nt]=(f32x4){0.f,0.f,0.f,0.f};

  #pragma unroll
  for(int k0=0;k0<256;k0+=32){
    short8 a[4], b[8];
    #pragma unroll
    for(int mi=0;mi<4;mi++)
      a[mi] = *(const short8*)(A1 + (size_t)(m0+mi*16+lr)*256 + k0 + lk);
    #pragma unroll
    for(int nt=0;nt<8;nt++){
      unsigned row = nt*16 + lr;
      unsigned baddr = row*512 + (k0+lk)*2;
      baddr ^= ((row&7u)<<4);
      b[nt] = *(const short8*)((char*)Bs + baddr);
    }
    #pragma unroll
    for(int mi=0;mi<4;mi++)
      #pragma unroll
      for(int nt=0;nt<8;nt++)
        acc[mi][nt] = __builtin_amdgcn_mfma_f32_16x16x32_bf16(a[mi],b[nt],acc[mi][nt],0,0,0);
  }

  if(MODE==0){
    __syncthreads();
    {
      const u16* src = B2 + (size_t)half*128*256;
      #pragma unroll
      for(int it=0; it<16; ++it){
        int idx = (it*256 + t)*8;
        short8 v = *(const short8*)(src + idx);
        unsigned baddr = (unsigned)idx*2;
        baddr ^= ((baddr>>9)&7u)<<4;
        *(short8*)((char*)Bs + baddr) = v;
      }
    }
    __syncthreads();
    #pragma unroll
    for(int k0=0;k0<256;k0+=32){
      short8 a[4], b[8];
      #pragma unroll
      for(int mi=0;mi<4;mi++)
        a[mi] = *(const short8*)(A2 + (size_t)(m0+mi*16+lr)*256 + k0 + lk);
      #pragma unroll
      for(int nt=0;nt<8;nt++){
        unsigned row = nt*16 + lr;
        unsigned baddr = row*512 + (k0+lk)*2;
        baddr ^= ((row&7u)<<4);
        b[nt] = *(const short8*)((char*)Bs + baddr);
      }
      #pragma unroll
      for(int mi=0;mi<4;mi++)
        #pragma unroll
        for(int nt=0;nt<8;nt++)
          acc[mi][nt] = __builtin_amdgcn_mfma_f32_16x16x32_bf16(a[mi],b[nt],acc[mi][nt],0,0,0);
    }
  }

  int rloc = (lane>>4)*4;
  #pragma unroll
  for(int mi=0;mi<4;mi++){
    #pragma unroll
    for(int j=0;j<4;j++){
      size_t r = m0 + mi*16 + rloc + j;
      float ex = (MODE==2)? extra[r] : 0.f;
      #pragma unroll
      for(int nt=0;nt<8;nt++){
        int c = half*128 + nt*16 + lr;
        float v = acc[mi][nt][j];
        if(MODE==1) v = silu_f(v + bias[c]);
        else if(MODE==2) v = v + ex*bias[c];
        else v = silu_f(v);
        outb[r*256 + c] = f2bf(v);
      }
    }
  }
}

// ---------------- logits GEMM + fused CE ----------------
// M=2048 (graphs), N=64 (50 valid), K=256. Block 256 thr / 4 waves, 16 rows/wave.
__global__ __launch_bounds__(256) void gemmL(const u16* __restrict__ A, const u16* __restrict__ Bt,
                      const float* __restrict__ bp2, const int* __restrict__ nl,
                      float* __restrict__ accum){
  int t = threadIdx.x;
  int wave = t>>6, lane = t&63;
  int m0 = blockIdx.x*64 + wave*16;
  int lr = lane&15, lk = (lane>>4)*8;
  f32x4 acc[4];
  #pragma unroll
  for(int nt=0;nt<4;nt++) acc[nt]=(f32x4){0.f,0.f,0.f,0.f};
  #pragma unroll
  for(int k0=0;k0<256;k0+=32){
    short8 a = *(const short8*)(A + (size_t)(m0+lr)*256 + k0 + lk);
    #pragma unroll
    for(int nt=0;nt<4;nt++){
      short8 b = *(const short8*)(Bt + (size_t)(nt*16+lr)*256 + k0 + lk);
      acc[nt] = __builtin_amdgcn_mfma_f32_16x16x32_bf16(a,b,acc[nt],0,0,0);
    }
  }
  // epilogue: per-row logsumexp - logit[target]
  float bp[4];
  #pragma unroll
  for(int nt=0;nt<4;nt++){
    int c = nt*16+lr;
    bp[nt] = (c<NL)? bp2[c] : 0.f;
  }
  float s = 0.f;
  #pragma unroll
  for(int j=0;j<4;j++){
    int r = m0 + (lane>>4)*4 + j;
    int tgt = nl[r];
    float mx = -1e30f, pk = 0.f;
    float lg[4];
    #pragma unroll
    for(int nt=0;nt<4;nt++){
      int c = nt*16+lr;
      lg[nt] = (c<NL)? (acc[nt][j] + bp[nt]) : -1e30f;
      mx = fmaxf(mx, lg[nt]);
      if(c==tgt) pk = lg[nt];
    }
    #pragma unroll
    for(int o=1;o<16;o<<=1) mx = fmaxf(mx, __shfl_xor(mx,o));
    float se = 0.f;
    #pragma unroll
    for(int nt=0;nt<4;nt++) se += __expf(lg[nt]-mx);
    #pragma unroll
    for(int o=1;o<16;o<<=1) se += __shfl_xor(se,o);
    #pragma unroll
    for(int o=1;o<16;o<<=1) pk += __shfl_xor(pk,o);
    s += logf(se)+mx - pk;
  }
  if((lane&15)==0) atomicAdd(&accum[1], s);
}

// ---------------- per-graph seg-sum of h1 -> bf16 ----------------
__global__ void k_sg(const u16* __restrict__ h1b, const int* __restrict__ gstart,
                     u16* __restrict__ sgb){
  int g = blockIdx.x, lane = threadIdx.x;
  int s0=gstart[g], s1=gstart[g+1];
  float a0=0.f,a1=0.f,a2=0.f,a3=0.f;
  for(int i=s0;i<s1;i++){
    us4 v = *(const us4*)(h1b + (size_t)i*256 + lane*4);
    a0+=bf2f(v.x); a1+=bf2f(v.y); a2+=bf2f(v.z); a3+=bf2f(v.w);
  }
  us4 o; o.x=f2bf(a0); o.y=f2bf(a1); o.z=f2bf(a2); o.w=f2bf(a3);
  *(us4*)(sgb + (size_t)g*256 + lane*4) = o;
}

// ---------------- fused edge-delta + denoise loss ----------------

__global__ void k_eloss(const int* __restrict__ start, const int* __restrict__ elist,
                        const float* __restrict__ posp, const float* __restrict__ cf,
                        const float* __restrict__ target, const float* __restrict__ sigg,
                        const int* __restrict__ n2g, float* __restrict__ accum){
  int i = blockIdx.x*256+threadIdx.x;
  float s=0.f;
  if(i<NN){
    int s0=start[i], s1=start[i+1];
    float px=posp[i*3+0], py=posp[i*3+1], pz=posp[i*3+2];
    float dx=0.f, dy=0.f, dz=0.f;
    for(int e=s0;e<s1;e++){
      int r=elist[e];
      float c=cf[r];
      dx += (posp[r*3+0]-px)*c;
      dy += (posp[r*3+1]-py)*c;
      dz += (posp[r*3+2]-pz)*c;
    }
    float is = 1.f/sigg[n2g[i]];
    float d0 = dx*is - target[i*3+0];
    float d1 = dy*is - target[i*3+1];
    float d2 = dz*is - target[i*3+2];
    s = d0*d0+d1*d1+d2*d2;
  }
  #pragma unroll
  for(int o=32;o;o>>=1) s += __shfl_down(s,o);
  if((threadIdx.x&63)==0) atomicAdd(&accum[0], s);
}

__global__ void k_final(const float* __restrict__ accum, float* __restrict__ out){
  out[0] = accum[0]/(float)NG;
  out[1] = accum[1]/(float)NG;
}

// ---------------- launcher ----------------

extern "C" void kernel_launch(void* const* d_in, const int* in_sizes, int n_in,
                              void* d_out, int out_size, void* d_ws, size_t ws_size,
                              hipStream_t stream){
  (void)in_sizes; (void)n_in; (void)out_size; (void)ws_size;
  const float* x      = (const float*)d_in[0];
  const float* pos    = (const float*)d_in[1];
  const float* noise  = (const float*)d_in[2];
  const int*   n2g    = (const int*)d_in[3];
  const int*   ei     = (const int*)d_in[4];
  const int*   nl     = (const int*)d_in[5];
  const float* W_node = (const float*)d_in[6];
  const float* W_msg  = (const float*)d_in[7];
  const float* w_gate = (const float*)d_in[8];
  const float* Wd1    = (const float*)d_in[9];
  const float* bd1    = (const float*)d_in[10];
  const float* Wd2    = (const float*)d_in[11];
  const float* bd2    = (const float*)d_in[12];
  const float* Wp1    = (const float*)d_in[17];
  const float* bp1    = (const float*)d_in[18];
  const float* Wp2    = (const float*)d_in[19];
  const float* bp2    = (const float*)d_in[20];
  float* out = (float*)d_out;

  char* w = (char*)d_ws;
  size_t off = 0;
  auto alloc = [&](size_t bytes)->void*{
    void* p = w + off;
    off += (bytes + 255) & ~(size_t)255;
    return p;
  };

  // --- zeroed region ---
  size_t zstart = off;
  int*   cnt_e   = (int*)alloc((size_t)NN*4);
  float* sum_pos = (float*)alloc((size_t)NG*3*4);
  float* sum_pp  = (float*)alloc((size_t)NG*3*4);
  float* Hm      = (float*)alloc((size_t)NG*9*4);
  float* accum   = (float*)alloc(2*4);
  size_t zend = off;

  // --- other buffers ---
  u16*  xb   = (u16*)alloc((size_t)NN*HD*2);
  u16*  xsb  = (u16*)alloc((size_t)NN*HD*2);
  u16*  xlb  = (u16*)alloc((size_t)NN*HD*2);
  u16*  h1b  = (u16*)alloc((size_t)NN*HD*2);
  u16*  sgb  = (u16*)alloc((size_t)NG*HD*2);
  u16*  xgb  = (u16*)alloc((size_t)NG*HD*2);
  u16*  hb   = (u16*)alloc((size_t)NG*HD*2);
  float* sigg   = (float*)alloc((size_t)NG*4);
  float* cntf   = (float*)alloc((size_t)NG*4);
  float* ppin   = (float*)alloc((size_t)NN*3*4);
  float* posp   = (float*)alloc((size_t)NN*3*4);
  float* target = (float*)alloc((size_t)NN*3*4);
  float* cf     = (float*)alloc((size_t)NN*4);
  float* center = (float*)alloc((size_t)NG*3*4);
  float* pcenter= (float*)alloc((size_t)NG*3*4);
  float* Rm     = (float*)alloc((size_t)NG*9*4);
  float* Tm     = (float*)alloc((size_t)NG*3*4);
  int*  gstart  = (int*)alloc((size_t)(NG+1)*4);
  int*  start   = (int*)alloc((size_t)(NN+1)*4);
  int*  cursor  = (int*)alloc((size_t)NN*4);
  int*  bsum    = (int*)alloc((size_t)256*4);
  int*  elist   = (int*)alloc((size_t)NE*4);
  u16*  wt_node = (u16*)alloc((size_t)HD*HD*2);
  u16*  wt_msg  = (u16*)alloc((size_t)HD*HD*2);
  u16*  wt_d1   = (u16*)alloc((size_t)HD*HD*2);
  u16*  wt_d2   = (u16*)alloc((size_t)HD*HD*2);
  u16*  wpet    = (u16*)alloc((size_t)HD*HD*2);
  u16*  wp2t    = (u16*)alloc((size_t)64*HD*2);
  float* wmg    = (float*)alloc((size_t)HD*4);

  hipMemsetAsync(w+zstart, 0, zend-zstart, stream);

  // graph structure
  k_gb    <<<(NN+256)/256,256,0,stream>>>(n2g,gstart);
  k_sigg  <<<NG/256,256,0,stream>>>(nl,sigg);
  k_cnt   <<<NG/256,256,0,stream>>>(gstart,cntf);

  // Kabsch path
  k_perturb<<<NN/256,256,0,stream>>>(pos,noise,n2g,sigg,ppin,sum_pos,sum_pp);
  k_center <<<NG/256,256,0,stream>>>(sum_pos,sum_pp,gstart,center,pcenter);
  k_H      <<<NN/256,256,0,stream>>>(pos,ppin,n2g,center,pcenter,Hm);
  k_polar  <<<NG/256,256,0,stream>>>(Hm,center,pcenter,Rm,Tm);
  k_posp   <<<NN/256,256,0,stream>>>(ppin,pos,sigg,n2g,Rm,Tm,posp,target);

  // prep
  k_wmg   <<<1,256,0,stream>>>(W_msg,w_gate,wmg);
  k_prep  <<<NN/4,256,0,stream>>>(x,wmg,xb,cf);
  k_wt    <<<(HD*HD)/256,256,0,stream>>>(W_node,wt_node);
  k_wt    <<<(HD*HD)/256,256,0,stream>>>(W_msg ,wt_msg);
  k_wt    <<<(HD*HD)/256,256,0,stream>>>(Wd1   ,wt_d1);
  k_wt    <<<(HD*HD)/256,256,0,stream>>>(Wd2   ,wt_d2);
  k_wpe   <<<(HD*HD)/256,256,0,stream>>>(Wp1,wpet);
  k_wp2   <<<(64*HD)/256,256,0,stream>>>(Wp2,wp2t);

  // CSR build
  k_count <<<NE/256,256,0,stream>>>(ei,cnt_e);
  k_scan_a<<<NN/256,256,0,stream>>>(cnt_e,start,bsum);
  k_scan_b<<<1,256,0,stream>>>(bsum);
  k_scan_c<<<NN/256,256,0,stream>>>(start,bsum,cursor);
  k_scatter<<<NE/256,256,0,stream>>>(ei,cursor,elist);

  // GNN
  k_gather<<<NN,64,0,stream>>>(xb,start,elist,xsb);
  gemmB<0><<<512,256,0,stream>>>(xb ,xsb,wt_node,wt_msg,nullptr,nullptr,xlb);  // xl
  gemmB<1><<<512,256,0,stream>>>(xlb,nullptr,wt_d1,nullptr,bd1,nullptr,h1b);   // h1

  // graph rep + head (ce)
  k_sg    <<<NG,64,0,stream>>>(h1b,gstart,sgb);
  gemmB<2><<<16,256,0,stream>>>(sgb,nullptr,wt_d2,nullptr,bd2,cntf,xgb);       // xg
  gemmB<1><<<16,256,0,stream>>>(xgb,nullptr,wpet,nullptr,bp1,nullptr,hb);      // h
  gemmL   <<<32,256,0,stream>>>(hb,wp2t,bp2,nl,accum);                         // ce

  // position branch + denoise loss
  k_eloss <<<NN/256,256,0,stream>>>(start,elist,posp,cf,target,sigg,n2g,accum);

  k_final <<<1,1,0,stream>>>(accum,out);
}

// Round 6
// 300.967 us; speedup vs baseline: 4.2233x; 1.3581x over previous
//
#include <hip/hip_runtime.h>
#include <math.h>

#define NN 65536   // nodes
#define NE 524288  // edges
#define NG 2048    // graphs
#define HD 256     // hidden
#define NL 50      // noise levels

typedef unsigned short u16;
typedef unsigned char u8;
typedef __attribute__((ext_vector_type(8))) short short8;
typedef __attribute__((ext_vector_type(4))) float f32x4;
typedef __attribute__((ext_vector_type(4))) unsigned short us4;

__device__ __forceinline__ float bf2f(u16 h){
  union{unsigned int u; float f;} v; v.u = ((unsigned int)h)<<16; return v.f;
}
__device__ __forceinline__ u16 f2bf(float f){
  union{float f; unsigned int u;} v; v.f=f;
  return (u16)((v.u + 0x7FFFu + ((v.u>>16)&1u))>>16);
}
__device__ __forceinline__ float silu_f(float v){ return v/(1.0f+__expf(-v)); }
__device__ __forceinline__ u8 f2e4m3(float v){
  return (u8)__builtin_amdgcn_cvt_pk_fp8_f32(v, v, 0, false);
}
__device__ __forceinline__ float4 e4m3x4(unsigned w){
  float4 r;
  r.x = __builtin_amdgcn_cvt_f32_fp8(w, 0);
  r.y = __builtin_amdgcn_cvt_f32_fp8(w, 1);
  r.z = __builtin_amdgcn_cvt_f32_fp8(w, 2);
  r.w = __builtin_amdgcn_cvt_f32_fp8(w, 3);
  return r;
}

#define WRED(v) { v += __shfl_xor(v,1); v += __shfl_xor(v,2); v += __shfl_xor(v,4); \
                  v += __shfl_xor(v,8); v += __shfl_xor(v,16); v += __shfl_xor(v,32); }

// ---------------- graph boundaries (n2g is sorted) ----------------
__global__ void k_gb(const int* __restrict__ n2g, int* __restrict__ gstart){
  int i = blockIdx.x*256 + threadIdx.x;
  if(i>NN) return;
  int cur  = (i<NN)? n2g[i] : NG;
  int prev = (i==0)? -1 : n2g[i-1];
  for(int g=prev+1; g<=cur; ++g) gstart[g]=i;
}

// ---------------- fused Kabsch: one wave per graph ----------------
__global__ __launch_bounds__(256) void k_kab(const float* __restrict__ pos,
        const float* __restrict__ noise, const int* __restrict__ gstart,
        const int* __restrict__ nl, float* __restrict__ sigg,
        float* __restrict__ posp, float* __restrict__ target){
  int wid = (blockIdx.x<<2) + (threadIdx.x>>6);   // graph id, 0..2047
  int lane = threadIdx.x & 63;
  int s0 = gstart[wid], s1 = gstart[wid+1];
  const double L0 =  2.3025850929940456840;  // ln 10
  const double L1 = -4.6051701859880913680;  // ln 0.01
  float sg = (float)exp(L0 + (double)nl[wid]*(L1-L0)/49.0);
  if(lane==0) sigg[wid]=sg;

  float sx=0,sy=0,sz=0, tx=0,ty=0,tz=0;
  for(int i=s0+lane;i<s1;i+=64){
    float px=pos[3*i],py=pos[3*i+1],pz=pos[3*i+2];
    sx+=px; sy+=py; sz+=pz;
    tx+=px+noise[3*i]*sg; ty+=py+noise[3*i+1]*sg; tz+=pz+noise[3*i+2]*sg;
  }
  WRED(sx); WRED(sy); WRED(sz); WRED(tx); WRED(ty); WRED(tz);
  float invc = 1.f/fmaxf((float)(s1-s0),1.f);
  float cx=sx*invc, cy=sy*invc, cz=sz*invc;
  float pcx=tx*invc, pcy=ty*invc, pcz=tz*invc;

  float h00=0,h01=0,h02=0,h10=0,h11=0,h12=0,h20=0,h21=0,h22=0;
  for(int i=s0+lane;i<s1;i+=64){
    float px=pos[3*i],py=pos[3*i+1],pz=pos[3*i+2];
    float a0=px+noise[3*i]*sg-pcx, a1=py+noise[3*i+1]*sg-pcy, a2=pz+noise[3*i+2]*sg-pcz;
    float b0=px-cx, b1=py-cy, b2=pz-cz;
    h00+=a0*b0; h01+=a0*b1; h02+=a0*b2;
    h10+=a1*b0; h11+=a1*b1; h12+=a1*b2;
    h20+=a2*b0; h21+=a2*b1; h22+=a2*b2;
  }
  WRED(h00); WRED(h01); WRED(h02); WRED(h10); WRED(h11); WRED(h12);
  WRED(h20); WRED(h21); WRED(h22);

  // X = H^T ; polar orthogonal factor via Newton (uniform across lanes)
  float X[3][3] = {{h00,h10,h20},{h01,h11,h21},{h02,h12,h22}};
  float nf=0.f;
  #pragma unroll
  for(int r=0;r<3;r++) for(int c=0;c<3;c++) nf += X[r][c]*X[r][c];
  nf = sqrtf(nf);
  if(nf < 1e-20f){
    #pragma unroll
    for(int r=0;r<3;r++) for(int c=0;c<3;c++) X[r][c]=(r==c)?1.f:0.f;
  } else {
    float s0f=1.f/nf;
    #pragma unroll
    for(int r=0;r<3;r++) for(int c=0;c<3;c++) X[r][c]*=s0f;
    for(int it=0; it<30; ++it){
      float a=X[0][0],b=X[0][1],c=X[0][2];
      float d=X[1][0],e=X[1][1],f=X[1][2];
      float gg=X[2][0],h=X[2][1],ii=X[2][2];
      float A_= e*ii-f*h, B_=-(d*ii-f*gg), C_= d*h-e*gg;
      float D_=-(b*ii-c*h), E_= a*ii-c*gg, F_=-(a*h-b*gg);
      float G_= b*f-c*e,  H_=-(a*f-c*d),  I_= a*e-b*d;
      float det = a*A_ + b*B_ + c*C_;
      if(!(fabsf(det) > 1e-25f)){
        if(it==0){
          for(int r=0;r<3;r++) for(int cc=0;cc<3;cc++) X[r][cc]=(r==cc)?1.f:0.f;
        }
        break;
      }
      float si = 0.5f/det;
      float Y00=0.5f*a + si*A_, Y01=0.5f*b + si*B_, Y02=0.5f*c + si*C_;
      float Y10=0.5f*d + si*D_, Y11=0.5f*e + si*E_, Y12=0.5f*f + si*F_;
      float Y20=0.5f*gg+ si*G_, Y21=0.5f*h + si*H_, Y22=0.5f*ii+ si*I_;
      X[0][0]=Y00; X[0][1]=Y01; X[0][2]=Y02;
      X[1][0]=Y10; X[1][1]=Y11; X[1][2]=Y12;
      X[2][0]=Y20; X[2][1]=Y21; X[2][2]=Y22;
    }
  }
  float T0 = cx - (X[0][0]*pcx + X[0][1]*pcy + X[0][2]*pcz);
  float T1 = cy - (X[1][0]*pcx + X[1][1]*pcy + X[1][2]*pcz);
  float T2 = cz - (X[2][0]*pcx + X[2][1]*pcy + X[2][2]*pcz);
  float is = 1.f/sg;
  for(int i=s0+lane;i<s1;i+=64){
    float px=pos[3*i],py=pos[3*i+1],pz=pos[3*i+2];
    float qx=px+noise[3*i]*sg, qy=py+noise[3*i+1]*sg, qz=pz+noise[3*i+2]*sg;
    float ox = X[0][0]*qx + X[0][1]*qy + X[0][2]*qz + T0;
    float oy = X[1][0]*qx + X[1][1]*qy + X[1][2]*qz + T1;
    float oz = X[2][0]*qx + X[2][1]*qy + X[2][2]*qz + T2;
    posp[3*i]=ox; posp[3*i+1]=oy; posp[3*i+2]=oz;
    target[3*i]=(px-ox)*is; target[3*i+1]=(py-oy)*is; target[3*i+2]=(pz-oz)*is;
  }
}

// ---------------- all weight prep in one launch ----------------
__global__ void k_wall(const float* __restrict__ Wn, const float* __restrict__ Wm,
                       const float* __restrict__ Wd1, const float* __restrict__ Wd2,
                       const float* __restrict__ Wp1, const float* __restrict__ Wp2,
                       const float* __restrict__ wgate,
                       u8* __restrict__ wn8, u8* __restrict__ wm8, u8* __restrict__ wd18,
                       u16* __restrict__ wd2b, u16* __restrict__ wpeb,
                       u16* __restrict__ wp2b, float* __restrict__ wmg){
  int b = blockIdx.x, t = threadIdx.x;
  if(b < 768){
    int m = b>>8;
    int idx = (b&255)*256 + t;
    int k = idx>>8, n = idx&255;
    const float* W = (m==0)? Wn : (m==1)? Wm : Wd1;
    u8* O = (m==0)? wn8 : (m==1)? wm8 : wd18;
    O[n*256+k] = f2e4m3(W[k*256+n]);
  } else if(b < 1024){
    int idx = (b-768)*256 + t; int k=idx>>8, n=idx&255;
    wd2b[n*256+k] = f2bf(Wd2[k*256+n]);
  } else if(b < 1280){
    int idx = (b-1024)*256 + t; int k=idx>>8, n=idx&255;
    wpeb[n*256+k] = f2bf(Wp1[k*256+n] + Wp1[(k+256)*256+n]);
  } else if(b < 1344){
    int idx = (b-1280)*256 + t; int k=idx&255, n=idx>>8;
    wp2b[n*256+k] = (n<NL)? f2bf(Wp2[k*NL+n]) : (u16)0;
  } else {
    float s=0.f;
    for(int j=0;j<256;j++) s += Wm[t*256+j]*wgate[j];
    wmg[t]=s;
  }
}

// ---------------- fused: xb8 = fp8(x), cf = silu(x . wmg) ----------------
__global__ void k_prep8(const float* __restrict__ x, const float* __restrict__ wmg,
                        u8* __restrict__ xb8, float* __restrict__ cf){
  int wave = threadIdx.x>>6, lane = threadIdx.x&63;
  int i = blockIdx.x*4 + wave;
  float4 a = ((const float4*)(x + (size_t)i*256))[lane];
  float4 b = ((const float4*)wmg)[lane];
  float s = a.x*b.x + a.y*b.y + a.z*b.z + a.w*b.w;
  unsigned w = __builtin_amdgcn_cvt_pk_fp8_f32(a.x, a.y, 0, false);
  w = __builtin_amdgcn_cvt_pk_fp8_f32(a.z, a.w, w, true);
  *(unsigned*)(xb8 + (size_t)i*256 + lane*4) = w;
  #pragma unroll
  for(int o=32;o;o>>=1) s += __shfl_down(s,o);
  if(lane==0) cf[i]=silu_f(s);
}

// ---------------- CSR build ----------------
__global__ void k_count(const int* __restrict__ ei, int* __restrict__ cnt_e){
  int e = blockIdx.x*256+threadIdx.x; if(e>=NE) return;
  atomicAdd(&cnt_e[ei[NE+e]],1);
}
__global__ void k_scan_a(const int* __restrict__ cnt_e, int* __restrict__ start,
                         int* __restrict__ bsum){
  __shared__ int sh[256];
  int b=blockIdx.x, t=threadIdx.x, i=b*256+t;
  int v = cnt_e[i]; sh[t]=v; __syncthreads();
  #pragma unroll
  for(int o=1;o<256;o<<=1){
    int u = (t>=o)? sh[t-o]:0; __syncthreads(); sh[t]+=u; __syncthreads();
  }
  start[i] = sh[t]-v;
  if(t==255) bsum[b]=sh[255];
}
__global__ void k_scan_b(int* __restrict__ bsum){
  __shared__ int sh[256];
  int t=threadIdx.x; int v=bsum[t]; sh[t]=v; __syncthreads();
  #pragma unroll
  for(int o=1;o<256;o<<=1){
    int u=(t>=o)?sh[t-o]:0; __syncthreads(); sh[t]+=u; __syncthreads();
  }
  bsum[t]=sh[t]-v;
}
__global__ void k_scan_c(int* __restrict__ start, const int* __restrict__ bsum,
                         int* __restrict__ cursor){
  int b=blockIdx.x, i=b*256+threadIdx.x;
  int v = start[i]+bsum[b];
  start[i]=v; cursor[i]=v;
  if(i==0) start[NN]=NE;
}
__global__ void k_scatter(const int* __restrict__ ei, int* __restrict__ cursor,
                          int* __restrict__ elist){
  int e = blockIdx.x*256+threadIdx.x; if(e>=NE) return;
  int c = ei[NE+e];
  int p = atomicAdd(&cursor[c],1);
  elist[p] = ei[e];
}

// ---------------- neighbor gather (fp8): xs[c] = sum xb[r] ----------------
__global__ void k_gather8(const u8* __restrict__ xb8, const int* __restrict__ start,
                          const int* __restrict__ elist, u8* __restrict__ xs8){
  int c = blockIdx.x, lane = threadIdx.x;
  int s0=start[c], s1=start[c+1];
  float a0=0.f,a1=0.f,a2=0.f,a3=0.f;
  int e=s0;
  for(; e+1<s1; e+=2){
    int r0=elist[e], r1=elist[e+1];
    unsigned w0 = *(const unsigned*)(xb8 + (size_t)r0*256 + lane*4);
    unsigned w1 = *(const unsigned*)(xb8 + (size_t)r1*256 + lane*4);
    float4 v0 = e4m3x4(w0), v1 = e4m3x4(w1);
    a0 += v0.x+v1.x; a1 += v0.y+v1.y; a2 += v0.z+v1.z; a3 += v0.w+v1.w;
  }
  if(e<s1){
    unsigned w0 = *(const unsigned*)(xb8 + (size_t)elist[e]*256 + lane*4);
    float4 v0 = e4m3x4(w0);
    a0+=v0.x; a1+=v0.y; a2+=v0.z; a3+=v0.w;
  }
  unsigned w = __builtin_amdgcn_cvt_pk_fp8_f32(a0, a1, 0, false);
  w = __builtin_amdgcn_cvt_pk_fp8_f32(a2, a3, w, true);
  *(unsigned*)(xs8 + (size_t)c*256 + lane*4) = w;
}

// ---------------- fused fp8 node GEMM chain ----------------
// h1 = silu( silu(xb@Wn^T + xs@Wm^T) @ Wd1^T + bd1 ), all fp8 in / fp8 out.
// 512 thr (8 waves), 128 rows/block, 16 rows/wave. LDS: Bs 32KB + XL 32KB.
__global__ __launch_bounds__(512) void gemmF8(
    const u8* __restrict__ A1, const u8* __restrict__ A2,
    const u8* __restrict__ Wn, const u8* __restrict__ Wm,
    const u8* __restrict__ Wd, const float* __restrict__ bd1,
    u8* __restrict__ outb){
  __shared__ u8 Bs[32768];
  __shared__ u8 XL[32768];
  int t = threadIdx.x;
  int wave = t>>6, lane = t&63;
  int lr = lane&15, lkgrp = lane>>4, lk8 = lkgrp*8;
  int m0 = blockIdx.x*128 + wave*16;
  char* xlw = (char*)XL + wave*4096;

  auto stage = [&](const u8* src){
    #pragma unroll
    for(int it=0; it<8; ++it){
      unsigned byte = (unsigned)(it*512 + t)*8;
      long v = *(const long*)(src + byte);
      unsigned dst = byte ^ (((byte>>8)&7u)<<3);
      *(long*)((char*)Bs + dst) = v;
    }
  };

  f32x4 acc[16];
  #pragma unroll
  for(int i=0;i<16;i++) acc[i]=(f32x4){0.f,0.f,0.f,0.f};

  // phase A: acc = xb@Wn^T + xs@Wm^T  (cols: acc[h*8+nt] -> h*128+nt*16+lr)
  for(int h=0; h<2; ++h){
    for(int m=0; m<2; ++m){
      __syncthreads();
      stage((m==0? Wn : Wm) + (size_t)h*32768);
      __syncthreads();
      const u8* Ab = (m==0? A1 : A2) + (size_t)(m0+lr)*256;
      #pragma unroll
      for(int k0=0;k0<256;k0+=32){
        long a = *(const long*)(Ab + k0 + lk8);
        #pragma unroll
        for(int nt=0;nt<8;++nt){
          unsigned row = nt*16+lr;
          unsigned byte = (row<<8) + k0 + lk8;
          byte ^= ((row&7u)<<3);
          long b = *(const long*)((const char*)Bs + byte);
          acc[h*8+nt] = __builtin_amdgcn_mfma_f32_16x16x32_fp8_fp8(a,b,acc[h*8+nt],0,0,0);
        }
      }
    }
  }

  // xl = silu(acc) -> per-wave XL (fp8, swizzled)
  #pragma unroll
  for(int nt=0;nt<16;++nt){
    #pragma unroll
    for(int j=0;j<4;++j){
      unsigned row = lkgrp*4 + j;
      unsigned col = nt*16 + lr;
      u8 p = f2e4m3(silu_f(acc[nt][j]));
      unsigned byte = (row<<8) + col;
      byte ^= (((row>>1)&7u)<<3);
      xlw[byte] = (char)p;
    }
  }

  // phase B: acc = xl@Wd1^T
  #pragma unroll
  for(int i=0;i<16;i++) acc[i]=(f32x4){0.f,0.f,0.f,0.f};
  for(int h=0;h<2;++h){
    __syncthreads();
    stage(Wd + (size_t)h*32768);
    __syncthreads();
    #pragma unroll
    for(int k0=0;k0<256;k0+=32){
      unsigned ab = ((unsigned)lr<<8) + k0 + lk8;
      ab ^= (((lr>>1)&7u)<<3);
      long a = *(const long*)(xlw + ab);
      #pragma unroll
      for(int nt=0;nt<8;++nt){
        unsigned row = nt*16+lr;
        unsigned byte = (row<<8) + k0 + lk8;
        byte ^= ((row&7u)<<3);
        long b = *(const long*)((const char*)Bs + byte);
        acc[h*8+nt] = __builtin_amdgcn_mfma_f32_16x16x32_fp8_fp8(a,b,acc[h*8+nt],0,0,0);
      }
    }
  }

  // epilogue: h1 = silu(acc + bd1) -> Bs transpose -> coalesced global
  __syncthreads();
  #pragma unroll
  for(int nt=0;nt<16;++nt){
    #pragma unroll
    for(int j=0;j<4;++j){
      unsigned row = wave*16 + lkgrp*4 + j;
      unsigned col = nt*16 + lr;
      u8 p = f2e4m3(silu_f(acc[nt][j] + bd1[col]));
      unsigned byte = (row<<8) + col;
      byte ^= (((row>>2)&3u)<<4);
      ((char*)Bs)[byte] = (char)p;
    }
  }
  __syncthreads();
  #pragma unroll
  for(int it=0; it<4; ++it){
    unsigned byte = (unsigned)(it*512 + t)*16;
    unsigned src = byte ^ (((byte>>10)&3u)<<4);
    short8 v = *(const short8*)((const char*)Bs + src);
    *(short8*)(outb + (size_t)blockIdx.x*32768 + byte) = v;
  }
}

// ---------------- per-graph seg-sum of h1 (fp8 in, bf16 out) ----------------
__global__ void k_sg8(const u8* __restrict__ h18, const int* __restrict__ gstart,
                      u16* __restrict__ sgb){
  int g = blockIdx.x, lane = threadIdx.x;
  int s0=gstart[g], s1=gstart[g+1];
  float a0=0.f,a1=0.f,a2=0.f,a3=0.f;
  for(int i=s0;i<s1;i++){
    unsigned w = *(const unsigned*)(h18 + (size_t)i*256 + lane*4);
    float4 v = e4m3x4(w);
    a0+=v.x; a1+=v.y; a2+=v.z; a3+=v.w;
  }
  us4 o; o.x=f2bf(a0); o.y=f2bf(a1); o.z=f2bf(a2); o.w=f2bf(a3);
  *(us4*)(sgb + (size_t)g*256 + lane*4) = o;
}

// ---------------- head GEMM (bf16, M=2048) ----------------
// MODE 1: out = bf16(silu(A@B^T + bias[c])) ; MODE 2: out = bf16(A@B^T + cnt[r]*bias[c])
template<int MODE>
__global__ __launch_bounds__(256,2) void gemmH(const u16* __restrict__ A,
                       const u16* __restrict__ Bt, const float* __restrict__ bias,
                       const int* __restrict__ gs, u16* __restrict__ outb){
  __shared__ u16 Bsh[128*256];
  int t = threadIdx.x;
  int wave = t>>6, lane = t&63;
  int half  = blockIdx.x & 1;
  int chunk = blockIdx.x >> 1;
  int m0 = chunk*256 + wave*64;
  int lr = lane&15, lk = (lane>>4)*8;
  {
    const u16* src = Bt + (size_t)half*128*256;
    #pragma unroll
    for(int it=0; it<16; ++it){
      int idx = (it*256 + t)*8;
      short8 v = *(const short8*)(src + idx);
      unsigned baddr = (unsigned)idx*2;
      baddr ^= ((baddr>>9)&7u)<<4;
      *(short8*)((char*)Bsh + baddr) = v;
    }
  }
  __syncthreads();
  f32x4 acc[4][8];
  #pragma unroll
  for(int mi=0;mi<4;mi++)
    #pragma unroll
    for(int nt=0;nt<8;nt++) acc[mi][nt]=(f32x4){0.f,0.f,0.f,0.f};
  #pragma unroll
  for(int k0=0;k0<256;k0+=32){
    short8 a[4], b[8];
    #pragma unroll
    for(int mi=0;mi<4;mi++)
      a[mi] = *(const short8*)(A + (size_t)(m0+mi*16+lr)*256 + k0 + lk);
    #pragma unroll
    for(int nt=0;nt<8;nt++){
      unsigned row = nt*16 + lr;
      unsigned baddr = row*512 + (k0+lk)*2;
      baddr ^= ((row&7u)<<4);
      b[nt] = *(const short8*)((char*)Bsh + baddr);
    }
    #pragma unroll
    for(int mi=0;mi<4;mi++)
      #pragma unroll
      for(int nt=0;nt<8;nt++)
        acc[mi][nt] = __builtin_amdgcn_mfma_f32_16x16x32_bf16(a[mi],b[nt],acc[mi][nt],0,0,0);
  }
  int rloc = (lane>>4)*4;
  #pragma unroll
  for(int mi=0;mi<4;mi++){
    #pragma unroll
    for(int j=0;j<4;j++){
      size_t r = m0 + mi*16 + rloc + j;
      float ex = (MODE==2)? (float)(gs[r+1]-gs[r]) : 0.f;
      #pragma unroll
      for(int nt=0;nt<8;nt++){
        int c = half*128 + nt*16 + lr;
        float v = acc[mi][nt][j];
        if(MODE==1) v = silu_f(v + bias[c]);
        else v = v + ex*bias[c];
        outb[r*256 + c] = f2bf(v);
      }
    }
  }
}

// ---------------- logits GEMM + fused CE ----------------
__global__ __launch_bounds__(256) void gemmL(const u16* __restrict__ A, const u16* __restrict__ Bt,
                      const float* __restrict__ bp2, const int* __restrict__ nl,
                      float* __restrict__ accum){
  int t = threadIdx.x;
  int wave = t>>6, lane = t&63;
  int m0 = blockIdx.x*64 + wave*16;
  int lr = lane&15, lk = (lane>>4)*8;
  f32x4 acc[4];
  #pragma unroll
  for(int nt=0;nt<4;nt++) acc[nt]=(f32x4){0.f,0.f,0.f,0.f};
  #pragma unroll
  for(int k0=0;k0<256;k0+=32){
    short8 a = *(const short8*)(A + (size_t)(m0+lr)*256 + k0 + lk);
    #pragma unroll
    for(int nt=0;nt<4;nt++){
      short8 b = *(const short8*)(Bt + (size_t)(nt*16+lr)*256 + k0 + lk);
      acc[nt] = __builtin_amdgcn_mfma_f32_16x16x32_bf16(a,b,acc[nt],0,0,0);
    }
  }
  float bp[4];
  #pragma unroll
  for(int nt=0;nt<4;nt++){
    int c = nt*16+lr;
    bp[nt] = (c<NL)? bp2[c] : 0.f;
  }
  float s = 0.f;
  #pragma unroll
  for(int j=0;j<4;j++){
    int r = m0 + (lane>>4)*4 + j;
    int tgt = nl[r];
    float mx = -1e30f, pk = 0.f;
    float lg[4];
    #pragma unroll
    for(int nt=0;nt<4;nt++){
      int c = nt*16+lr;
      lg[nt] = (c<NL)? (acc[nt][j] + bp[nt]) : -1e30f;
      mx = fmaxf(mx, lg[nt]);
      if(c==tgt) pk = lg[nt];
    }
    #pragma unroll
    for(int o=1;o<16;o<<=1) mx = fmaxf(mx, __shfl_xor(mx,o));
    float se = 0.f;
    #pragma unroll
    for(int nt=0;nt<4;nt++) se += __expf(lg[nt]-mx);
    #pragma unroll
    for(int o=1;o<16;o<<=1) se += __shfl_xor(se,o);
    #pragma unroll
    for(int o=1;o<16;o<<=1) pk += __shfl_xor(pk,o);
    s += logf(se)+mx - pk;
  }
  if((lane&15)==0) atomicAdd(&accum[1], s);
}

// ---------------- fused edge-delta + denoise loss ----------------
__global__ void k_eloss(const int* __restrict__ start, const int* __restrict__ elist,
                        const float* __restrict__ posp, const float* __restrict__ cf,
                        const float* __restrict__ target, const float* __restrict__ sigg,
                        const int* __restrict__ n2g, float* __restrict__ accum){
  int i = blockIdx.x*256+threadIdx.x;
  float s=0.f;
  if(i<NN){
    int s0=start[i], s1=start[i+1];
    float px=posp[i*3+0], py=posp[i*3+1], pz=posp[i*3+2];
    float dx=0.f, dy=0.f, dz=0.f;
    for(int e=s0;e<s1;e++){
      int r=elist[e];
      float c=cf[r];
      dx += (posp[r*3+0]-px)*c;
      dy += (posp[r*3+1]-py)*c;
      dz += (posp[r*3+2]-pz)*c;
    }
    float is = 1.f/sigg[n2g[i]];
    float d0 = dx*is - target[i*3+0];
    float d1 = dy*is - target[i*3+1];
    float d2 = dz*is - target[i*3+2];
    s = d0*d0+d1*d1+d2*d2;
  }
  #pragma unroll
  for(int o=32;o;o>>=1) s += __shfl_down(s,o);
  if((threadIdx.x&63)==0) atomicAdd(&accum[0], s);
}

__global__ void k_final(const float* __restrict__ accum, float* __restrict__ out){
  out[0] = accum[0]/(float)NG;
  out[1] = accum[1]/(float)NG;
}

// ---------------- launcher ----------------
extern "C" void kernel_launch(void* const* d_in, const int* in_sizes, int n_in,
                              void* d_out, int out_size, void* d_ws, size_t ws_size,
                              hipStream_t stream){
  (void)in_sizes; (void)n_in; (void)out_size; (void)ws_size;
  const float* x      = (const float*)d_in[0];
  const float* pos    = (const float*)d_in[1];
  const float* noise  = (const float*)d_in[2];
  const int*   n2g    = (const int*)d_in[3];
  const int*   ei     = (const int*)d_in[4];
  const int*   nl     = (const int*)d_in[5];
  const float* W_node = (const float*)d_in[6];
  const float* W_msg  = (const float*)d_in[7];
  const float* w_gate = (const float*)d_in[8];
  const float* Wd1    = (const float*)d_in[9];
  const float* bd1    = (const float*)d_in[10];
  const float* Wd2    = (const float*)d_in[11];
  const float* bd2    = (const float*)d_in[12];
  const float* Wp1    = (const float*)d_in[17];
  const float* bp1    = (const float*)d_in[18];
  const float* Wp2    = (const float*)d_in[19];
  const float* bp2    = (const float*)d_in[20];
  float* out = (float*)d_out;

  char* w = (char*)d_ws;
  size_t off = 0;
  auto alloc = [&](size_t bytes)->void*{
    void* p = w + off;
    off += (bytes + 255) & ~(size_t)255;
    return p;
  };

  // --- zeroed region ---
  size_t zstart = off;
  int*   cnt_e   = (int*)alloc((size_t)NN*4);
  float* accum   = (float*)alloc(2*4);
  size_t zend = off;

  // --- other buffers ---
  u8*   xb8  = (u8*)alloc((size_t)NN*HD);
  u8*   xs8  = (u8*)alloc((size_t)NN*HD);
  u8*   h18  = (u8*)alloc((size_t)NN*HD);
  u16*  sgb  = (u16*)alloc((size_t)NG*HD*2);
  u16*  xgb  = (u16*)alloc((size_t)NG*HD*2);
  u16*  hb   = (u16*)alloc((size_t)NG*HD*2);
  float* sigg   = (float*)alloc((size_t)NG*4);
  float* posp   = (float*)alloc((size_t)NN*3*4);
  float* target = (float*)alloc((size_t)NN*3*4);
  float* cf     = (float*)alloc((size_t)NN*4);
  int*  gstart  = (int*)alloc((size_t)(NG+1)*4);
  int*  start   = (int*)alloc((size_t)(NN+1)*4);
  int*  cursor  = (int*)alloc((size_t)NN*4);
  int*  bsum    = (int*)alloc((size_t)256*4);
  int*  elist   = (int*)alloc((size_t)NE*4);
  u8*   wn8     = (u8*)alloc((size_t)HD*HD);
  u8*   wm8     = (u8*)alloc((size_t)HD*HD);
  u8*   wd18    = (u8*)alloc((size_t)HD*HD);
  u16*  wd2b    = (u16*)alloc((size_t)HD*HD*2);
  u16*  wpeb    = (u16*)alloc((size_t)HD*HD*2);
  u16*  wp2b    = (u16*)alloc((size_t)64*HD*2);
  float* wmg    = (float*)alloc((size_t)HD*4);

  (void)hipMemsetAsync(w+zstart, 0, zend-zstart, stream);

  // graph structure + Kabsch
  k_gb   <<<(NN+256)/256,256,0,stream>>>(n2g,gstart);
  k_kab  <<<NG/4,256,0,stream>>>(pos,noise,gstart,nl,sigg,posp,target);

  // weights + node features
  k_wall <<<1345,256,0,stream>>>(W_node,W_msg,Wd1,Wd2,Wp1,Wp2,w_gate,
                                 wn8,wm8,wd18,wd2b,wpeb,wp2b,wmg);
  k_prep8<<<NN/4,256,0,stream>>>(x,wmg,xb8,cf);

  // CSR build
  k_count <<<NE/256,256,0,stream>>>(ei,cnt_e);
  k_scan_a<<<NN/256,256,0,stream>>>(cnt_e,start,bsum);
  k_scan_b<<<1,256,0,stream>>>(bsum);
  k_scan_c<<<NN/256,256,0,stream>>>(start,bsum,cursor);
  k_scatter<<<NE/256,256,0,stream>>>(ei,cursor,elist);

  // GNN node chain (fused, fp8)
  k_gather8<<<NN,64,0,stream>>>(xb8,start,elist,xs8);
  gemmF8   <<<512,512,0,stream>>>(xb8,xs8,wn8,wm8,wd18,bd1,h18);

  // graph rep + head (ce)
  k_sg8   <<<NG,64,0,stream>>>(h18,gstart,sgb);
  gemmH<2><<<16,256,0,stream>>>(sgb,wd2b,bd2,gstart,xgb);
  gemmH<1><<<16,256,0,stream>>>(xgb,wpeb,bp1,nullptr,hb);
  gemmL   <<<32,256,0,stream>>>(hb,wp2b,bp2,nl,accum);

  // position branch + denoise loss
  k_eloss <<<NN/256,256,0,stream>>>(start,elist,posp,cf,target,sigg,n2g,accum);

  k_final <<<1,1,0,stream>>>(accum,out);
}

// Round 7
// 291.921 us; speedup vs baseline: 4.3541x; 1.0310x over previous
//
#include <hip/hip_runtime.h>
#include <math.h>

#define NN 65536   // nodes
#define NE 524288  // edges
#define NG 2048    // graphs
#define HD 256     // hidden
#define NL 50      // noise levels

typedef unsigned short u16;
typedef unsigned char u8;
typedef __attribute__((ext_vector_type(8))) short short8;
typedef __attribute__((ext_vector_type(4))) float f32x4;
typedef __attribute__((ext_vector_type(4))) unsigned short us4;

__device__ __forceinline__ float bf2f(u16 h){
  union{unsigned int u; float f;} v; v.u = ((unsigned int)h)<<16; return v.f;
}
__device__ __forceinline__ u16 f2bf(float f){
  union{float f; unsigned int u;} v; v.f=f;
  return (u16)((v.u + 0x7FFFu + ((v.u>>16)&1u))>>16);
}
__device__ __forceinline__ float silu_f(float v){ return v/(1.0f+__expf(-v)); }
__device__ __forceinline__ u8 f2e4m3(float v){
  return (u8)__builtin_amdgcn_cvt_pk_fp8_f32(v, v, 0, false);
}
__device__ __forceinline__ float4 e4m3x4(unsigned w){
  float4 r;
  r.x = __builtin_amdgcn_cvt_f32_fp8(w, 0);
  r.y = __builtin_amdgcn_cvt_f32_fp8(w, 1);
  r.z = __builtin_amdgcn_cvt_f32_fp8(w, 2);
  r.w = __builtin_amdgcn_cvt_f32_fp8(w, 3);
  return r;
}

#define WRED(v) { v += __shfl_xor(v,1); v += __shfl_xor(v,2); v += __shfl_xor(v,4); \
                  v += __shfl_xor(v,8); v += __shfl_xor(v,16); v += __shfl_xor(v,32); }

// ---------------- graph boundaries (n2g is sorted) ----------------
__global__ void k_gb(const int* __restrict__ n2g, int* __restrict__ gstart){
  int i = blockIdx.x*256 + threadIdx.x;
  if(i>NN) return;
  int cur  = (i<NN)? n2g[i] : NG;
  int prev = (i==0)? -1 : n2g[i-1];
  for(int g=prev+1; g<=cur; ++g) gstart[g]=i;
}

// ---------------- fused Kabsch: one wave per graph ----------------
__global__ __launch_bounds__(256) void k_kab(const float* __restrict__ pos,
        const float* __restrict__ noise, const int* __restrict__ gstart,
        const int* __restrict__ nl, float* __restrict__ sigg,
        float* __restrict__ posp, float* __restrict__ target){
  int wid = (blockIdx.x<<2) + (threadIdx.x>>6);   // graph id, 0..2047
  int lane = threadIdx.x & 63;
  int s0 = gstart[wid], s1 = gstart[wid+1];
  const double L0 =  2.3025850929940456840;  // ln 10
  const double L1 = -4.6051701859880913680;  // ln 0.01
  float sg = (float)exp(L0 + (double)nl[wid]*(L1-L0)/49.0);
  if(lane==0) sigg[wid]=sg;

  float sx=0,sy=0,sz=0, tx=0,ty=0,tz=0;
  for(int i=s0+lane;i<s1;i+=64){
    float px=pos[3*i],py=pos[3*i+1],pz=pos[3*i+2];
    sx+=px; sy+=py; sz+=pz;
    tx+=px+noise[3*i]*sg; ty+=py+noise[3*i+1]*sg; tz+=pz+noise[3*i+2]*sg;
  }
  WRED(sx); WRED(sy); WRED(sz); WRED(tx); WRED(ty); WRED(tz);
  float invc = 1.f/fmaxf((float)(s1-s0),1.f);
  float cx=sx*invc, cy=sy*invc, cz=sz*invc;
  float pcx=tx*invc, pcy=ty*invc, pcz=tz*invc;

  float h00=0,h01=0,h02=0,h10=0,h11=0,h12=0,h20=0,h21=0,h22=0;
  for(int i=s0+lane;i<s1;i+=64){
    float px=pos[3*i],py=pos[3*i+1],pz=pos[3*i+2];
    float a0=px+noise[3*i]*sg-pcx, a1=py+noise[3*i+1]*sg-pcy, a2=pz+noise[3*i+2]*sg-pcz;
    float b0=px-cx, b1=py-cy, b2=pz-cz;
    h00+=a0*b0; h01+=a0*b1; h02+=a0*b2;
    h10+=a1*b0; h11+=a1*b1; h12+=a1*b2;
    h20+=a2*b0; h21+=a2*b1; h22+=a2*b2;
  }
  WRED(h00); WRED(h01); WRED(h02); WRED(h10); WRED(h11); WRED(h12);
  WRED(h20); WRED(h21); WRED(h22);

  // X = H^T ; polar orthogonal factor via Newton (uniform across lanes)
  float X[3][3] = {{h00,h10,h20},{h01,h11,h21},{h02,h12,h22}};
  float nf=0.f;
  #pragma unroll
  for(int r=0;r<3;r++) for(int c=0;c<3;c++) nf += X[r][c]*X[r][c];
  nf = sqrtf(nf);
  if(nf < 1e-20f){
    #pragma unroll
    for(int r=0;r<3;r++) for(int c=0;c<3;c++) X[r][c]=(r==c)?1.f:0.f;
  } else {
    float s0f=1.f/nf;
    #pragma unroll
    for(int r=0;r<3;r++) for(int c=0;c<3;c++) X[r][c]*=s0f;
    for(int it=0; it<30; ++it){
      float a=X[0][0],b=X[0][1],c=X[0][2];
      float d=X[1][0],e=X[1][1],f=X[1][2];
      float gg=X[2][0],h=X[2][1],ii=X[2][2];
      float A_= e*ii-f*h, B_=-(d*ii-f*gg), C_= d*h-e*gg;
      float D_=-(b*ii-c*h), E_= a*ii-c*gg, F_=-(a*h-b*gg);
      float G_= b*f-c*e,  H_=-(a*f-c*d),  I_= a*e-b*d;
      float det = a*A_ + b*B_ + c*C_;
      if(!(fabsf(det) > 1e-25f)){
        if(it==0){
          for(int r=0;r<3;r++) for(int cc=0;cc<3;cc++) X[r][cc]=(r==cc)?1.f:0.f;
        }
        break;
      }
      float si = 0.5f/det;
      float Y00=0.5f*a + si*A_, Y01=0.5f*b + si*B_, Y02=0.5f*c + si*C_;
      float Y10=0.5f*d + si*D_, Y11=0.5f*e + si*E_, Y12=0.5f*f + si*F_;
      float Y20=0.5f*gg+ si*G_, Y21=0.5f*h + si*H_, Y22=0.5f*ii+ si*I_;
      X[0][0]=Y00; X[0][1]=Y01; X[0][2]=Y02;
      X[1][0]=Y10; X[1][1]=Y11; X[1][2]=Y12;
      X[2][0]=Y20; X[2][1]=Y21; X[2][2]=Y22;
    }
  }
  float T0 = cx - (X[0][0]*pcx + X[0][1]*pcy + X[0][2]*pcz);
  float T1 = cy - (X[1][0]*pcx + X[1][1]*pcy + X[1][2]*pcz);
  float T2 = cz - (X[2][0]*pcx + X[2][1]*pcy + X[2][2]*pcz);
  float is = 1.f/sg;
  for(int i=s0+lane;i<s1;i+=64){
    float px=pos[3*i],py=pos[3*i+1],pz=pos[3*i+2];
    float qx=px+noise[3*i]*sg, qy=py+noise[3*i+1]*sg, qz=pz+noise[3*i+2]*sg;
    float ox = X[0][0]*qx + X[0][1]*qy + X[0][2]*qz + T0;
    float oy = X[1][0]*qx + X[1][1]*qy + X[1][2]*qz + T1;
    float oz = X[2][0]*qx + X[2][1]*qy + X[2][2]*qz + T2;
    posp[3*i]=ox; posp[3*i+1]=oy; posp[3*i+2]=oz;
    target[3*i]=(px-ox)*is; target[3*i+1]=(py-oy)*is; target[3*i+2]=(pz-oz)*is;
  }
}

// ---------------- all weight prep in one launch ----------------
__global__ void k_wall(const float* __restrict__ Wn, const float* __restrict__ Wm,
                       const float* __restrict__ Wd1, const float* __restrict__ Wd2,
                       const float* __restrict__ Wp1, const float* __restrict__ Wp2,
                       const float* __restrict__ wgate,
                       u8* __restrict__ wn8, u8* __restrict__ wm8, u8* __restrict__ wd18,
                       u16* __restrict__ wd2b, u16* __restrict__ wpeb,
                       u16* __restrict__ wp2b, float* __restrict__ wmg){
  int b = blockIdx.x, t = threadIdx.x;
  if(b < 768){
    int m = b>>8;
    int idx = (b&255)*256 + t;
    int k = idx>>8, n = idx&255;
    const float* W = (m==0)? Wn : (m==1)? Wm : Wd1;
    u8* O = (m==0)? wn8 : (m==1)? wm8 : wd18;
    O[n*256+k] = f2e4m3(W[k*256+n]);
  } else if(b < 1024){
    int idx = (b-768)*256 + t; int k=idx>>8, n=idx&255;
    wd2b[n*256+k] = f2bf(Wd2[k*256+n]);
  } else if(b < 1280){
    int idx = (b-1024)*256 + t; int k=idx>>8, n=idx&255;
    wpeb[n*256+k] = f2bf(Wp1[k*256+n] + Wp1[(k+256)*256+n]);
  } else if(b < 1344){
    int idx = (b-1280)*256 + t; int k=idx&255, n=idx>>8;
    wp2b[n*256+k] = (n<NL)? f2bf(Wp2[k*NL+n]) : (u16)0;
  } else {
    float s=0.f;
    for(int j=0;j<256;j++) s += Wm[t*256+j]*wgate[j];
    wmg[t]=s;
  }
}

// ---------------- fused: xb8 = fp8(x), cf = silu(x . wmg) ----------------
__global__ void k_prep8(const float* __restrict__ x, const float* __restrict__ wmg,
                        u8* __restrict__ xb8, float* __restrict__ cf){
  int wave = threadIdx.x>>6, lane = threadIdx.x&63;
  int i = blockIdx.x*4 + wave;
  float4 a = ((const float4*)(x + (size_t)i*256))[lane];
  float4 b = ((const float4*)wmg)[lane];
  float s = a.x*b.x + a.y*b.y + a.z*b.z + a.w*b.w;
  unsigned w = __builtin_amdgcn_cvt_pk_fp8_f32(a.x, a.y, 0, false);
  w = __builtin_amdgcn_cvt_pk_fp8_f32(a.z, a.w, w, true);
  *(unsigned*)(xb8 + (size_t)i*256 + lane*4) = w;
  #pragma unroll
  for(int o=32;o;o>>=1) s += __shfl_down(s,o);
  if(lane==0) cf[i]=silu_f(s);
}

// ---------------- CSR build ----------------
__global__ void k_count(const int* __restrict__ ei, int* __restrict__ cnt_e){
  int e = blockIdx.x*256+threadIdx.x; if(e>=NE) return;
  atomicAdd(&cnt_e[ei[NE+e]],1);
}
__global__ void k_scan_a(const int* __restrict__ cnt_e, int* __restrict__ start,
                         int* __restrict__ bsum){
  __shared__ int sh[256];
  int b=blockIdx.x, t=threadIdx.x, i=b*256+t;
  int v = cnt_e[i]; sh[t]=v; __syncthreads();
  #pragma unroll
  for(int o=1;o<256;o<<=1){
    int u = (t>=o)? sh[t-o]:0; __syncthreads(); sh[t]+=u; __syncthreads();
  }
  start[i] = sh[t]-v;
  if(t==255) bsum[b]=sh[255];
}
__global__ void k_scan_b(int* __restrict__ bsum){
  __shared__ int sh[256];
  int t=threadIdx.x; int v=bsum[t]; sh[t]=v; __syncthreads();
  #pragma unroll
  for(int o=1;o<256;o<<=1){
    int u=(t>=o)?sh[t-o]:0; __syncthreads(); sh[t]+=u; __syncthreads();
  }
  bsum[t]=sh[t]-v;
}
__global__ void k_scan_c(int* __restrict__ start, const int* __restrict__ bsum,
                         int* __restrict__ cursor){
  int b=blockIdx.x, i=b*256+threadIdx.x;
  int v = start[i]+bsum[b];
  start[i]=v; cursor[i]=v;
  if(i==0) start[NN]=NE;
}
__global__ void k_scatter(const int* __restrict__ ei, int* __restrict__ cursor,
                          int* __restrict__ elist){
  int e = blockIdx.x*256+threadIdx.x; if(e>=NE) return;
  int c = ei[NE+e];
  int p = atomicAdd(&cursor[c],1);
  elist[p] = ei[e];
}

// ---------------- neighbor gather (fp8): xs[c] = sum xb[r] ----------------
__global__ void k_gather8(const u8* __restrict__ xb8, const int* __restrict__ start,
                          const int* __restrict__ elist, u8* __restrict__ xs8){
  int c = blockIdx.x, lane = threadIdx.x;
  int s0=start[c], s1=start[c+1];
  float a0=0.f,a1=0.f,a2=0.f,a3=0.f;
  int e=s0;
  for(; e+3<s1; e+=4){
    int r0=elist[e], r1=elist[e+1], r2=elist[e+2], r3=elist[e+3];
    unsigned w0 = *(const unsigned*)(xb8 + (size_t)r0*256 + lane*4);
    unsigned w1 = *(const unsigned*)(xb8 + (size_t)r1*256 + lane*4);
    unsigned w2 = *(const unsigned*)(xb8 + (size_t)r2*256 + lane*4);
    unsigned w3 = *(const unsigned*)(xb8 + (size_t)r3*256 + lane*4);
    float4 v0 = e4m3x4(w0), v1 = e4m3x4(w1), v2 = e4m3x4(w2), v3 = e4m3x4(w3);
    a0 += (v0.x+v1.x)+(v2.x+v3.x); a1 += (v0.y+v1.y)+(v2.y+v3.y);
    a2 += (v0.z+v1.z)+(v2.z+v3.z); a3 += (v0.w+v1.w)+(v2.w+v3.w);
  }
  for(; e<s1; ++e){
    unsigned w0 = *(const unsigned*)(xb8 + (size_t)elist[e]*256 + lane*4);
    float4 v0 = e4m3x4(w0);
    a0+=v0.x; a1+=v0.y; a2+=v0.z; a3+=v0.w;
  }
  unsigned w = __builtin_amdgcn_cvt_pk_fp8_f32(a0, a1, 0, false);
  w = __builtin_amdgcn_cvt_pk_fp8_f32(a2, a3, w, true);
  *(unsigned*)(xs8 + (size_t)c*256 + lane*4) = w;
}

// ---------------- fused fp8 node GEMM chain (swapped operands) ----------------
// h1 = silu( silu(xb@Wn^T + xs@Wm^T) @ Wd1^T + bd1 ), fp8 in / fp8 out.
// 512 thr (8 waves), 128 rows/block, 16 nodes/wave.
// mfma(a=W-frag, b=x-frag): D[feature][node] -> lane holds node lr,
// features lkgrp*4+j -> dword-packed LDS staging, conflict-free under
// swz(b) = b ^ (((b>>8)&15)<<3)  (row-XOR into byte bits 3..6).
__global__ __launch_bounds__(512) void gemmF8(
    const u8* __restrict__ A1, const u8* __restrict__ A2,
    const u8* __restrict__ Wn, const u8* __restrict__ Wm,
    const u8* __restrict__ Wd, const float* __restrict__ bd1,
    u8* __restrict__ outb){
  __shared__ u8 Bs[32768];
  __shared__ u8 XL[32768];
  int t = threadIdx.x;
  int wave = t>>6, lane = t&63;
  int lr = lane&15, lkgrp = lane>>4, lk8 = lkgrp*8;
  int m0 = blockIdx.x*128 + wave*16;
  char* xlw = (char*)XL + wave*4096;

  auto stage = [&](const u8* src){
    #pragma unroll
    for(int it=0; it<8; ++it){
      unsigned byte = (unsigned)(it*512 + t)*8;
      long v = *(const long*)(src + byte);
      unsigned dst = byte ^ (((byte>>8)&15u)<<3);
      *(long*)((char*)Bs + dst) = v;
    }
  };

  f32x4 acc[16];
  #pragma unroll
  for(int i=0;i<16;i++) acc[i]=(f32x4){0.f,0.f,0.f,0.f};

  // phase A: acc[h*8+nt] = D[feat][node], feat = h*128+nt*16+lkgrp*4+j, node = lr
  for(int h=0; h<2; ++h){
    for(int m=0; m<2; ++m){
      __syncthreads();
      stage((m==0? Wn : Wm) + (size_t)h*32768);
      __syncthreads();
      const u8* Ab = (m==0? A1 : A2) + (size_t)(m0+lr)*256;
      #pragma unroll
      for(int k0=0;k0<256;k0+=32){
        long bx = *(const long*)(Ab + k0 + lk8);      // B-operand: node fragment
        #pragma unroll
        for(int nt=0;nt<8;++nt){
          unsigned row = nt*16+lr;                    // weight row within half
          unsigned byte = (row<<8) + k0 + lk8;
          byte ^= ((row&15u)<<3);
          long a = *(const long*)((const char*)Bs + byte);  // A-operand: weight fragment
          acc[h*8+nt] = __builtin_amdgcn_mfma_f32_16x16x32_fp8_fp8(a,bx,acc[h*8+nt],0,0,0);
        }
      }
    }
  }

  // xl = silu(acc) -> per-wave XL, dword writes (4 consecutive features / node)
  #pragma unroll
  for(int h=0;h<2;++h){
    #pragma unroll
    for(int nt=0;nt<8;++nt){
      f32x4 v = acc[h*8+nt];
      unsigned pk = __builtin_amdgcn_cvt_pk_fp8_f32(silu_f(v[0]), silu_f(v[1]), 0, false);
      pk = __builtin_amdgcn_cvt_pk_fp8_f32(silu_f(v[2]), silu_f(v[3]), pk, true);
      unsigned byte = ((unsigned)lr<<8) + h*128 + nt*16 + lkgrp*4;
      byte ^= ((lr&15u)<<3);
      *(unsigned*)(xlw + byte) = pk;
    }
  }

  // phase B: acc = D[feat][node] of xl@Wd1^T
  #pragma unroll
  for(int i=0;i<16;i++) acc[i]=(f32x4){0.f,0.f,0.f,0.f};
  for(int h=0;h<2;++h){
    __syncthreads();
    stage(Wd + (size_t)h*32768);
    __syncthreads();
    #pragma unroll
    for(int k0=0;k0<256;k0+=32){
      unsigned ab = ((unsigned)lr<<8) + k0 + lk8;
      ab ^= ((lr&15u)<<3);
      long bx = *(const long*)(xlw + ab);             // B-operand: xl node fragment
      #pragma unroll
      for(int nt=0;nt<8;++nt){
        unsigned row = nt*16+lr;
        unsigned byte = (row<<8) + k0 + lk8;
        byte ^= ((row&15u)<<3);
        long a = *(const long*)((const char*)Bs + byte);
        acc[h*8+nt] = __builtin_amdgcn_mfma_f32_16x16x32_fp8_fp8(a,bx,acc[h*8+nt],0,0,0);
      }
    }
  }

  // epilogue: h1 = silu(acc + bd1) -> Bs (dword, swizzled) -> coalesced 8B copy
  __syncthreads();
  #pragma unroll
  for(int h=0;h<2;++h){
    #pragma unroll
    for(int nt=0;nt<8;++nt){
      f32x4 v = acc[h*8+nt];
      int F = h*128 + nt*16 + lkgrp*4;
      unsigned pk = __builtin_amdgcn_cvt_pk_fp8_f32(silu_f(v[0]+bd1[F+0]), silu_f(v[1]+bd1[F+1]), 0, false);
      pk = __builtin_amdgcn_cvt_pk_fp8_f32(silu_f(v[2]+bd1[F+2]), silu_f(v[3]+bd1[F+3]), pk, true);
      unsigned row = (unsigned)(wave*16 + lr);
      unsigned byte = (row<<8) + (unsigned)F;
      byte ^= ((row&15u)<<3);
      *(unsigned*)((char*)Bs + byte) = pk;
    }
  }
  __syncthreads();
  #pragma unroll
  for(int it=0; it<8; ++it){
    unsigned byte = (unsigned)(it*512 + t)*8;
    unsigned src = byte ^ (((byte>>8)&15u)<<3);
    long v = *(const long*)((const char*)Bs + src);
    *(long*)(outb + (size_t)blockIdx.x*32768 + byte) = v;
  }
}

// ---------------- per-graph seg-sum of h1 (fp8 in, bf16 out) ----------------
__global__ void k_sg8(const u8* __restrict__ h18, const int* __restrict__ gstart,
                      u16* __restrict__ sgb){
  int g = blockIdx.x, lane = threadIdx.x;
  int s0=gstart[g], s1=gstart[g+1];
  float a0=0.f,a1=0.f,a2=0.f,a3=0.f;
  for(int i=s0;i<s1;i++){
    unsigned w = *(const unsigned*)(h18 + (size_t)i*256 + lane*4);
    float4 v = e4m3x4(w);
    a0+=v.x; a1+=v.y; a2+=v.z; a3+=v.w;
  }
  us4 o; o.x=f2bf(a0); o.y=f2bf(a1); o.z=f2bf(a2); o.w=f2bf(a3);
  *(us4*)(sgb + (size_t)g*256 + lane*4) = o;
}

// ---------------- head GEMM (bf16, M=2048) ----------------
template<int MODE>
__global__ __launch_bounds__(256,2) void gemmH(const u16* __restrict__ A,
                       const u16* __restrict__ Bt, const float* __restrict__ bias,
                       const int* __restrict__ gs, u16* __restrict__ outb){
  __shared__ u16 Bsh[128*256];
  int t = threadIdx.x;
  int wave = t>>6, lane = t&63;
  int half  = blockIdx.x & 1;
  int chunk = blockIdx.x >> 1;
  int m0 = chunk*256 + wave*64;
  int lr = lane&15, lk = (lane>>4)*8;
  {
    const u16* src = Bt + (size_t)half*128*256;
    #pragma unroll
    for(int it=0; it<16; ++it){
      int idx = (it*256 + t)*8;
      short8 v = *(const short8*)(src + idx);
      unsigned baddr = (unsigned)idx*2;
      baddr ^= ((baddr>>9)&7u)<<4;
      *(short8*)((char*)Bsh + baddr) = v;
    }
  }
  __syncthreads();
  f32x4 acc[4][8];
  #pragma unroll
  for(int mi=0;mi<4;mi++)
    #pragma unroll
    for(int nt=0;nt<8;nt++) acc[mi][nt]=(f32x4){0.f,0.f,0.f,0.f};
  #pragma unroll
  for(int k0=0;k0<256;k0+=32){
    short8 a[4], b[8];
    #pragma unroll
    for(int mi=0;mi<4;mi++)
      a[mi] = *(const short8*)(A + (size_t)(m0+mi*16+lr)*256 + k0 + lk);
    #pragma unroll
    for(int nt=0;nt<8;nt++){
      unsigned row = nt*16 + lr;
      unsigned baddr = row*512 + (k0+lk)*2;
      baddr ^= ((row&7u)<<4);
      b[nt] = *(const short8*)((char*)Bsh + baddr);
    }
    #pragma unroll
    for(int mi=0;mi<4;mi++)
      #pragma unroll
      for(int nt=0;nt<8;nt++)
        acc[mi][nt] = __builtin_amdgcn_mfma_f32_16x16x32_bf16(a[mi],b[nt],acc[mi][nt],0,0,0);
  }
  int rloc = (lane>>4)*4;
  #pragma unroll
  for(int mi=0;mi<4;mi++){
    #pragma unroll
    for(int j=0;j<4;j++){
      size_t r = m0 + mi*16 + rloc + j;
      float ex = (MODE==2)? (float)(gs[r+1]-gs[r]) : 0.f;
      #pragma unroll
      for(int nt=0;nt<8;nt++){
        int c = half*128 + nt*16 + lr;
        float v = acc[mi][nt][j];
        if(MODE==1) v = silu_f(v + bias[c]);
        else v = v + ex*bias[c];
        outb[r*256 + c] = f2bf(v);
      }
    }
  }
}

// ---------------- logits GEMM + fused CE ----------------
__global__ __launch_bounds__(256) void gemmL(const u16* __restrict__ A, const u16* __restrict__ Bt,
                      const float* __restrict__ bp2, const int* __restrict__ nl,
                      float* __restrict__ accum){
  int t = threadIdx.x;
  int wave = t>>6, lane = t&63;
  int m0 = blockIdx.x*64 + wave*16;
  int lr = lane&15, lk = (lane>>4)*8;
  f32x4 acc[4];
  #pragma unroll
  for(int nt=0;nt<4;nt++) acc[nt]=(f32x4){0.f,0.f,0.f,0.f};
  #pragma unroll
  for(int k0=0;k0<256;k0+=32){
    short8 a = *(const short8*)(A + (size_t)(m0+lr)*256 + k0 + lk);
    #pragma unroll
    for(int nt=0;nt<4;nt++){
      short8 b = *(const short8*)(Bt + (size_t)(nt*16+lr)*256 + k0 + lk);
      acc[nt] = __builtin_amdgcn_mfma_f32_16x16x32_bf16(a,b,acc[nt],0,0,0);
    }
  }
  float bp[4];
  #pragma unroll
  for(int nt=0;nt<4;nt++){
    int c = nt*16+lr;
    bp[nt] = (c<NL)? bp2[c] : 0.f;
  }
  float s = 0.f;
  #pragma unroll
  for(int j=0;j<4;j++){
    int r = m0 + (lane>>4)*4 + j;
    int tgt = nl[r];
    float mx = -1e30f, pk = 0.f;
    float lg[4];
    #pragma unroll
    for(int nt=0;nt<4;nt++){
      int c = nt*16+lr;
      lg[nt] = (c<NL)? (acc[nt][j] + bp[nt]) : -1e30f;
      mx = fmaxf(mx, lg[nt]);
      if(c==tgt) pk = lg[nt];
    }
    #pragma unroll
    for(int o=1;o<16;o<<=1) mx = fmaxf(mx, __shfl_xor(mx,o));
    float se = 0.f;
    #pragma unroll
    for(int nt=0;nt<4;nt++) se += __expf(lg[nt]-mx);
    #pragma unroll
    for(int o=1;o<16;o<<=1) se += __shfl_xor(se,o);
    #pragma unroll
    for(int o=1;o<16;o<<=1) pk += __shfl_xor(pk,o);
    s += logf(se)+mx - pk;
  }
  if((lane&15)==0) atomicAdd(&accum[1], s);
}

// ---------------- fused edge-delta + denoise loss ----------------
__global__ void k_eloss(const int* __restrict__ start, const int* __restrict__ elist,
                        const float* __restrict__ posp, const float* __restrict__ cf,
                        const float* __restrict__ target, const float* __restrict__ sigg,
                        const int* __restrict__ n2g, float* __restrict__ accum){
  int i = blockIdx.x*256+threadIdx.x;
  float s=0.f;
  if(i<NN){
    int s0=start[i], s1=start[i+1];
    float px=posp[i*3+0], py=posp[i*3+1], pz=posp[i*3+2];
    float dx=0.f, dy=0.f, dz=0.f;
    for(int e=s0;e<s1;e++){
      int r=elist[e];
      float c=cf[r];
      dx += (posp[r*3+0]-px)*c;
      dy += (posp[r*3+1]-py)*c;
      dz += (posp[r*3+2]-pz)*c;
    }
    float is = 1.f/sigg[n2g[i]];
    float d0 = dx*is - target[i*3+0];
    float d1 = dy*is - target[i*3+1];
    float d2 = dz*is - target[i*3+2];
    s = d0*d0+d1*d1+d2*d2;
  }
  #pragma unroll
  for(int o=32;o;o>>=1) s += __shfl_down(s,o);
  if((threadIdx.x&63)==0) atomicAdd(&accum[0], s);
}

__global__ void k_final(const float* __restrict__ accum, float* __restrict__ out){
  out[0] = accum[0]/(float)NG;
  out[1] = accum[1]/(float)NG;
}

// ---------------- launcher ----------------
extern "C" void kernel_launch(void* const* d_in, const int* in_sizes, int n_in,
                              void* d_out, int out_size, void* d_ws, size_t ws_size,
                              hipStream_t stream){
  (void)in_sizes; (void)n_in; (void)out_size; (void)ws_size;
  const float* x      = (const float*)d_in[0];
  const float* pos    = (const float*)d_in[1];
  const float* noise  = (const float*)d_in[2];
  const int*   n2g    = (const int*)d_in[3];
  const int*   ei     = (const int*)d_in[4];
  const int*   nl     = (const int*)d_in[5];
  const float* W_node = (const float*)d_in[6];
  const float* W_msg  = (const float*)d_in[7];
  const float* w_gate = (const float*)d_in[8];
  const float* Wd1    = (const float*)d_in[9];
  const float* bd1    = (const float*)d_in[10];
  const float* Wd2    = (const float*)d_in[11];
  const float* bd2    = (const float*)d_in[12];
  const float* Wp1    = (const float*)d_in[17];
  const float* bp1    = (const float*)d_in[18];
  const float* Wp2    = (const float*)d_in[19];
  const float* bp2    = (const float*)d_in[20];
  float* out = (float*)d_out;

  char* w = (char*)d_ws;
  size_t off = 0;
  auto alloc = [&](size_t bytes)->void*{
    void* p = w + off;
    off += (bytes + 255) & ~(size_t)255;
    return p;
  };

  // --- zeroed region ---
  size_t zstart = off;
  int*   cnt_e   = (int*)alloc((size_t)NN*4);
  float* accum   = (float*)alloc(2*4);
  size_t zend = off;

  // --- other buffers ---
  u8*   xb8  = (u8*)alloc((size_t)NN*HD);
  u8*   xs8  = (u8*)alloc((size_t)NN*HD);
  u8*   h18  = (u8*)alloc((size_t)NN*HD);
  u16*  sgb  = (u16*)alloc((size_t)NG*HD*2);
  u16*  xgb  = (u16*)alloc((size_t)NG*HD*2);
  u16*  hb   = (u16*)alloc((size_t)NG*HD*2);
  float* sigg   = (float*)alloc((size_t)NG*4);
  float* posp   = (float*)alloc((size_t)NN*3*4);
  float* target = (float*)alloc((size_t)NN*3*4);
  float* cf     = (float*)alloc((size_t)NN*4);
  int*  gstart  = (int*)alloc((size_t)(NG+1)*4);
  int*  start   = (int*)alloc((size_t)(NN+1)*4);
  int*  cursor  = (int*)alloc((size_t)NN*4);
  int*  bsum    = (int*)alloc((size_t)256*4);
  int*  elist   = (int*)alloc((size_t)NE*4);
  u8*   wn8     = (u8*)alloc((size_t)HD*HD);
  u8*   wm8     = (u8*)alloc((size_t)HD*HD);
  u8*   wd18    = (u8*)alloc((size_t)HD*HD);
  u16*  wd2b    = (u16*)alloc((size_t)HD*HD*2);
  u16*  wpeb    = (u16*)alloc((size_t)HD*HD*2);
  u16*  wp2b    = (u16*)alloc((size_t)64*HD*2);
  float* wmg    = (float*)alloc((size_t)HD*4);

  (void)hipMemsetAsync(w+zstart, 0, zend-zstart, stream);

  // graph structure + Kabsch
  k_gb   <<<(NN+256)/256,256,0,stream>>>(n2g,gstart);
  k_kab  <<<NG/4,256,0,stream>>>(pos,noise,gstart,nl,sigg,posp,target);

  // weights + node features
  k_wall <<<1345,256,0,stream>>>(W_node,W_msg,Wd1,Wd2,Wp1,Wp2,w_gate,
                                 wn8,wm8,wd18,wd2b,wpeb,wp2b,wmg);
  k_prep8<<<NN/4,256,0,stream>>>(x,wmg,xb8,cf);

  // CSR build
  k_count <<<NE/256,256,0,stream>>>(ei,cnt_e);
  k_scan_a<<<NN/256,256,0,stream>>>(cnt_e,start,bsum);
  k_scan_b<<<1,256,0,stream>>>(bsum);
  k_scan_c<<<NN/256,256,0,stream>>>(start,bsum,cursor);
  k_scatter<<<NE/256,256,0,stream>>>(ei,cursor,elist);

  // GNN node chain (fused, fp8)
  k_gather8<<<NN,64,0,stream>>>(xb8,start,elist,xs8);
  gemmF8   <<<512,512,0,stream>>>(xb8,xs8,wn8,wm8,wd18,bd1,h18);

  // graph rep + head (ce)
  k_sg8   <<<NG,64,0,stream>>>(h18,gstart,sgb);
  gemmH<2><<<16,256,0,stream>>>(sgb,wd2b,bd2,gstart,xgb);
  gemmH<1><<<16,256,0,stream>>>(xgb,wpeb,bp1,nullptr,hb);
  gemmL   <<<32,256,0,stream>>>(hb,wp2b,bp2,nl,accum);

  // position branch + denoise loss
  k_eloss <<<NN/256,256,0,stream>>>(start,elist,posp,cf,target,sigg,n2g,accum);

  k_final <<<1,1,0,stream>>>(accum,out);
}